// Round 7
// baseline (1118.548 us; speedup 1.0000x reference)
//
#include <hip/hip_runtime.h>
#include <hip/hip_bf16.h>
#include <cstdint>

#define HID 128

__device__ __forceinline__ unsigned pack_bf16(float a, float b)
{
    __hip_bfloat16 ha = __float2bfloat16(a);
    __hip_bfloat16 hb = __float2bfloat16(b);
    unsigned short ua = *reinterpret_cast<unsigned short*>(&ha);
    unsigned short ub = *reinterpret_cast<unsigned short*>(&hb);
    return (unsigned)ua | ((unsigned)ub << 16);
}

__device__ __forceinline__ float bf16_lo(unsigned u)
{
    unsigned v = u << 16;
    return *reinterpret_cast<float*>(&v);
}
__device__ __forceinline__ float bf16_hi(unsigned u)
{
    unsigned v = u & 0xffff0000u;
    return *reinterpret_cast<float*>(&v);
}

// ---------------------------------------------------------------------------
// Encoder GEMM: [N,768] @ [768,32] for des (y=0) and tweet (y=1).
// Block: 512 threads -> 256 nodes x 32 cols. K-chunk 32.
// Register-prefetch double buffering (spill-safe at acc[4][4], VGPR ~60<128).
// ---------------------------------------------------------------------------
#define ENC_BN 256
#define ENC_KC 32

__global__ __launch_bounds__(512, 4) void enc_gemm_kernel(
    const float* __restrict__ des, const float* __restrict__ tweet,
    const float* __restrict__ Wd, const float* __restrict__ bd,
    const float* __restrict__ Wt, const float* __restrict__ bt,
    float* __restrict__ x0, int N)
{
    __shared__ float At[ENC_KC][ENC_BN];   // XOR-swizzled cols
    __shared__ float Wl[ENC_KC][32];
    const int mat = blockIdx.y;
    const float* __restrict__ X = mat ? tweet : des;
    const float* __restrict__ W = mat ? Wt : Wd;
    const float* __restrict__ B = mat ? bt : bd;
    const int n0 = blockIdx.x * ENC_BN;
    const int t = threadIdx.x;          // 0..511
    const int cg = t & 7;               // 4 cols each
    const int ng = t >> 3;              // 0..63, 4 nodes each

    float acc[4][4] = {};

    const int f4 = t & 7;
    const int rbase = t >> 3;           // 0..63
    const int sw = 4 * f4;

    float4 preA[4];
    float4 preW;

    // prologue: prefetch chunk 0
    #pragma unroll
    for (int i = 0; i < 4; ++i) {
        int node = n0 + rbase + 64 * i;
        preA[i] = make_float4(0.f, 0.f, 0.f, 0.f);
        if (node < N)
            preA[i] = *reinterpret_cast<const float4*>(X + (size_t)node * 768 + f4 * 4);
    }
    if (t < 256)
        preW = *reinterpret_cast<const float4*>(W + (size_t)(t >> 3) * 32 + (t & 7) * 4);

    for (int k0 = 0; k0 < 768; k0 += ENC_KC) {
        // commit staged regs to LDS
        #pragma unroll
        for (int i = 0; i < 4; ++i) {
            int row = rbase + 64 * i;
            int colw = row ^ sw;
            At[f4 * 4 + 0][colw] = preA[i].x;
            At[f4 * 4 + 1][colw] = preA[i].y;
            At[f4 * 4 + 2][colw] = preA[i].z;
            At[f4 * 4 + 3][colw] = preA[i].w;
        }
        if (t < 256)
            *reinterpret_cast<float4*>(&Wl[t >> 3][(t & 7) * 4]) = preW;
        __syncthreads();

        // prefetch chunk k0+KC (latency hides under compute below)
        int k1 = k0 + ENC_KC;
        if (k1 < 768) {
            #pragma unroll
            for (int i = 0; i < 4; ++i) {
                int node = n0 + rbase + 64 * i;
                preA[i] = make_float4(0.f, 0.f, 0.f, 0.f);
                if (node < N)
                    preA[i] = *reinterpret_cast<const float4*>(X + (size_t)node * 768 + k1 + f4 * 4);
            }
            if (t < 256)
                preW = *reinterpret_cast<const float4*>(W + (size_t)(k1 + (t >> 3)) * 32 + (t & 7) * 4);
        }

        #pragma unroll
        for (int k = 0; k < ENC_KC; ++k) {
            int fk = 4 * ((k >> 2) & 7);
            int c0 = (ng * 4) ^ fk;
            float4 a = *reinterpret_cast<const float4*>(&At[k][c0]);
            float4 w = *reinterpret_cast<const float4*>(&Wl[k][cg * 4]);
            float av[4] = {a.x, a.y, a.z, a.w};
            float wc[4] = {w.x, w.y, w.z, w.w};
            #pragma unroll
            for (int j = 0; j < 4; ++j)
                #pragma unroll
                for (int c = 0; c < 4; ++c)
                    acc[j][c] = fmaf(av[j], wc[c], acc[j][c]);
        }
        __syncthreads();
    }

    float4 bb = *reinterpret_cast<const float4*>(B + cg * 4);
    float bc[4] = {bb.x, bb.y, bb.z, bb.w};
    #pragma unroll
    for (int j = 0; j < 4; ++j) {
        int node = n0 + ng * 4 + j;
        if (node >= N) break;
        float4 o;
        float v0 = acc[j][0] + bc[0]; o.x = v0 > 0.f ? v0 : 0.01f * v0;
        float v1 = acc[j][1] + bc[1]; o.y = v1 > 0.f ? v1 : 0.01f * v1;
        float v2 = acc[j][2] + bc[2]; o.z = v2 > 0.f ? v2 : 0.01f * v2;
        float v3 = acc[j][3] + bc[3]; o.w = v3 > 0.f ? v3 : 0.01f * v3;
        *reinterpret_cast<float4*>(x0 + (size_t)node * HID + mat * 32 + cg * 4) = o;
    }
}

// x0[:,64:96] = lrelu(num @ W_num + b), x0[:,96:128] = lrelu(cat @ W_cat + b)
__global__ void enc_nc_kernel(const float* __restrict__ num, const float* __restrict__ cat,
                              const float* __restrict__ Wn, const float* __restrict__ bn,
                              const float* __restrict__ Wc, const float* __restrict__ bc,
                              float* __restrict__ x0, int N)
{
    int tid = blockIdx.x * blockDim.x + threadIdx.x;
    int col = tid & 63;
    int node = tid >> 6;
    if (node >= N) return;
    float a;
    if (col < 32) {
        const float* r = num + (size_t)node * 5;
        float acc = bn[col];
        #pragma unroll
        for (int k = 0; k < 5; ++k) acc = fmaf(r[k], Wn[k * 32 + col], acc);
        a = acc;
    } else {
        int c = col & 31;
        a = fmaf(cat[node], Wc[c], bc[c]);
    }
    a = a > 0.f ? a : 0.01f * a;
    x0[(size_t)node * HID + 64 + col] = a;
}

// ---------------------------------------------------------------------------
// Dense [N,128] @ [128,128]. Block: 512 threads -> 128 nodes x 128 cols.
// Register-prefetch double buffering. BF16OUT for conv feeds.
// ---------------------------------------------------------------------------
template<bool BIAS, bool LRELU, bool DINV, bool BF16OUT>
__global__ __launch_bounds__(512, 4) void gemm128_kernel(
    const float* __restrict__ in, const float* __restrict__ W,
    const float* __restrict__ b, const float* __restrict__ dinv,
    void* __restrict__ outp, int N)
{
    __shared__ float At[32][128];   // XOR-swizzled cols
    __shared__ float Wl[32][128];
    const int n0 = blockIdx.x * 128;
    const int t = threadIdx.x;      // 0..511
    const int cg = t & 15;          // cols {cg*4, 64+cg*4}
    const int ng = t >> 4;          // 0..31, 4 nodes each

    float acc[4][8] = {};

    const int f4 = t & 7;
    const int rbase = t >> 3;       // 0..63
    const int sw = 4 * f4;
    const int wf = t & 31;
    const int kk = t >> 5;          // 0..15

    float4 preA[2], preW[2];
    #pragma unroll
    for (int i = 0; i < 2; ++i) {
        int node = n0 + rbase + 64 * i;
        preA[i] = make_float4(0.f, 0.f, 0.f, 0.f);
        if (node < N)
            preA[i] = *reinterpret_cast<const float4*>(in + (size_t)node * HID + f4 * 4);
        preW[i] = *reinterpret_cast<const float4*>(W + (size_t)(kk + 16 * i) * HID + wf * 4);
    }

    for (int k0 = 0; k0 < 128; k0 += 32) {
        #pragma unroll
        for (int i = 0; i < 2; ++i) {
            int row = rbase + 64 * i;
            int colw = row ^ sw;
            At[f4 * 4 + 0][colw] = preA[i].x;
            At[f4 * 4 + 1][colw] = preA[i].y;
            At[f4 * 4 + 2][colw] = preA[i].z;
            At[f4 * 4 + 3][colw] = preA[i].w;
            *reinterpret_cast<float4*>(&Wl[kk + 16 * i][wf * 4]) = preW[i];
        }
        __syncthreads();

        int k1 = k0 + 32;
        if (k1 < 128) {
            #pragma unroll
            for (int i = 0; i < 2; ++i) {
                int node = n0 + rbase + 64 * i;
                preA[i] = make_float4(0.f, 0.f, 0.f, 0.f);
                if (node < N)
                    preA[i] = *reinterpret_cast<const float4*>(in + (size_t)node * HID + k1 + f4 * 4);
                preW[i] = *reinterpret_cast<const float4*>(W + (size_t)(k1 + kk + 16 * i) * HID + wf * 4);
            }
        }

        #pragma unroll
        for (int k = 0; k < 32; ++k) {
            int fk = 4 * ((k >> 2) & 7);
            int c0 = (ng * 4) ^ fk;
            float4 a  = *reinterpret_cast<const float4*>(&At[k][c0]);
            float4 w0 = *reinterpret_cast<const float4*>(&Wl[k][cg * 4]);
            float4 w1 = *reinterpret_cast<const float4*>(&Wl[k][64 + cg * 4]);
            float av[4] = {a.x, a.y, a.z, a.w};
            float wc[8] = {w0.x, w0.y, w0.z, w0.w, w1.x, w1.y, w1.z, w1.w};
            #pragma unroll
            for (int j = 0; j < 4; ++j)
                #pragma unroll
                for (int c = 0; c < 8; ++c)
                    acc[j][c] = fmaf(av[j], wc[c], acc[j][c]);
        }
        __syncthreads();
    }

    float bc[8];
    if (BIAS) {
        float4 b0 = *reinterpret_cast<const float4*>(b + cg * 4);
        float4 b1 = *reinterpret_cast<const float4*>(b + 64 + cg * 4);
        bc[0]=b0.x; bc[1]=b0.y; bc[2]=b0.z; bc[3]=b0.w;
        bc[4]=b1.x; bc[5]=b1.y; bc[6]=b1.z; bc[7]=b1.w;
    }
    #pragma unroll
    for (int j = 0; j < 4; ++j) {
        int node = n0 + ng * 4 + j;
        if (node >= N) break;
        float di;
        if (DINV) di = dinv[node];
        float o[8];
        #pragma unroll
        for (int c = 0; c < 8; ++c) {
            float a = acc[j][c];
            if (BIAS)  a += bc[c];
            if (LRELU) a = a > 0.f ? a : 0.01f * a;
            if (DINV)  a *= di;
            o[c] = a;
        }
        if (BF16OUT) {
            unsigned* row = reinterpret_cast<unsigned*>(outp) + (size_t)node * (HID / 2);
            uint2 s0 = make_uint2(pack_bf16(o[0], o[1]), pack_bf16(o[2], o[3]));
            uint2 s1 = make_uint2(pack_bf16(o[4], o[5]), pack_bf16(o[6], o[7]));
            *reinterpret_cast<uint2*>(row + cg * 2)      = s0;
            *reinterpret_cast<uint2*>(row + 32 + cg * 2) = s1;
        } else {
            float* out = reinterpret_cast<float*>(outp);
            float4 s0 = make_float4(o[0], o[1], o[2], o[3]);
            float4 s1 = make_float4(o[4], o[5], o[6], o[7]);
            *reinterpret_cast<float4*>(out + (size_t)node * HID + cg * 4)      = s0;
            *reinterpret_cast<float4*>(out + (size_t)node * HID + 64 + cg * 4) = s1;
        }
    }
}

// ---------------------------------------------------------------------------
// CSR build: histogram -> exclusive scan -> range-partitioned scatter
// ---------------------------------------------------------------------------
__global__ void hist_kernel(const int* __restrict__ dst, int* __restrict__ cnt, int E)
{
    int i = blockIdx.x * blockDim.x + threadIdx.x;
    int stride = gridDim.x * blockDim.x;
    for (; i < E; i += stride) atomicAdd(&cnt[dst[i]], 1);
}

__global__ void scan_block_kernel(const int* __restrict__ cnt, int* __restrict__ excl_out,
                                  int* __restrict__ part, int N)
{
    __shared__ int s[256];
    int t = threadIdx.x;
    int i = blockIdx.x * 256 + t;
    int v = (i < N) ? cnt[i] : 0;
    s[t] = v;
    __syncthreads();
    #pragma unroll
    for (int off = 1; off < 256; off <<= 1) {
        int x = (t >= off) ? s[t - off] : 0;
        __syncthreads();
        s[t] += x;
        __syncthreads();
    }
    int incl = s[t];
    if (i < N) excl_out[i] = incl - v;
    if (t == 255) part[blockIdx.x] = incl;
}

__global__ void scan_part_kernel(int* __restrict__ part, int B)
{
    __shared__ int s[512];
    int t = threadIdx.x;
    int v = (t < B) ? part[t] : 0;
    s[t] = v;
    __syncthreads();
    #pragma unroll
    for (int off = 1; off < 512; off <<= 1) {
        int x = (t >= off) ? s[t - off] : 0;
        __syncthreads();
        s[t] += x;
        __syncthreads();
    }
    int incl = s[t];
    if (t < B) part[t] = incl - v;
    if (t == B - 1) part[B] = incl;
}

__global__ void scan_final_kernel(int* __restrict__ row_ptr, const int* __restrict__ part,
                                  int* __restrict__ cursor, const int* __restrict__ cnt,
                                  float* __restrict__ dinv, int N, int B)
{
    int i = blockIdx.x * blockDim.x + threadIdx.x;
    if (i < N) {
        int rp = row_ptr[i] + part[i >> 8];
        row_ptr[i] = rp;
        cursor[i] = rp;
        dinv[i] = rsqrtf((float)(cnt[i] + 1));
    } else if (i == N) {
        row_ptr[N] = part[B];
    }
}

__global__ void scatter_kernel(const int* __restrict__ src, const int* __restrict__ dst,
                               int* __restrict__ cursor, int* __restrict__ col_idx,
                               int E, int lo, int hi)
{
    int i = blockIdx.x * blockDim.x + threadIdx.x;
    int stride = gridDim.x * blockDim.x;
    for (; i < E; i += stride) {
        int d = dst[i];
        if (d >= lo && d < hi) {
            int pos = atomicAdd(&cursor[d], 1);
            col_idx[pos] = src[i];
        }
    }
}

// ---------------------------------------------------------------------------
// GCN gather (bf16 hs): out[i] = dinv[i] * (hs[i] + sum hs[src]) + b
// 32 lanes per node, 4 bf16 (8B) per lane. Accumulate f32, write f32.
// ---------------------------------------------------------------------------
__global__ void conv_gather_bf16_kernel(const unsigned* __restrict__ hs,
                                        const int* __restrict__ row_ptr,
                                        const int* __restrict__ col_idx,
                                        const float* __restrict__ dinv,
                                        const float* __restrict__ b,
                                        float* __restrict__ out, int N)
{
    int tid = blockIdx.x * blockDim.x + threadIdx.x;
    int node = tid >> 5;
    int f4 = tid & 31;
    if (node >= N) return;
    const uint2* base = reinterpret_cast<const uint2*>(hs);
    float a0, a1, a2, a3;
    {
        uint2 v = base[(size_t)node * 32 + f4];
        a0 = bf16_lo(v.x); a1 = bf16_hi(v.x);
        a2 = bf16_lo(v.y); a3 = bf16_hi(v.y);
    }
    int e = row_ptr[node], end = row_ptr[node + 1];
    while (e < end) {
        int m = end - e;
        if (m >= 32) {
            int idx = col_idx[e + f4];
            #pragma unroll 8
            for (int j = 0; j < 32; ++j) {
                int s = __shfl(idx, j, 32);
                uint2 v = base[(size_t)s * 32 + f4];
                a0 += bf16_lo(v.x); a1 += bf16_hi(v.x);
                a2 += bf16_lo(v.y); a3 += bf16_hi(v.y);
            }
            e += 32;
        } else {
            int idx = (f4 < m) ? col_idx[e + f4] : 0;
            for (int j = 0; j < m; ++j) {
                int s = __shfl(idx, j, 32);
                uint2 v = base[(size_t)s * 32 + f4];
                a0 += bf16_lo(v.x); a1 += bf16_hi(v.x);
                a2 += bf16_lo(v.y); a3 += bf16_hi(v.y);
            }
            e = end;
        }
    }
    float di = dinv[node];
    float4 b4 = reinterpret_cast<const float4*>(b)[f4];
    float4 o;
    o.x = fmaf(di, a0, b4.x);
    o.y = fmaf(di, a1, b4.y);
    o.z = fmaf(di, a2, b4.z);
    o.w = fmaf(di, a3, b4.w);
    reinterpret_cast<float4*>(out)[(size_t)node * 32 + f4] = o;
}

// ---------------------------------------------------------------------------
// Final: out[n,0:2] = y[n] @ W_o2 + b_o2. One wave per node.
// ---------------------------------------------------------------------------
__global__ void out_kernel(const float* __restrict__ y, const float* __restrict__ W,
                           const float* __restrict__ b, float* __restrict__ out, int N)
{
    int tid = blockIdx.x * blockDim.x + threadIdx.x;
    int lane = tid & 63;
    int node = tid >> 6;
    if (node >= N) return;
    const float* r = y + (size_t)node * HID;
    float v0 = r[lane], v1 = r[lane + 64];
    float p0 = v0 * W[lane * 2 + 0] + v1 * W[(lane + 64) * 2 + 0];
    float p1 = v0 * W[lane * 2 + 1] + v1 * W[(lane + 64) * 2 + 1];
    #pragma unroll
    for (int off = 32; off; off >>= 1) {
        p0 += __shfl_down(p0, off);
        p1 += __shfl_down(p1, off);
    }
    if (lane == 0) {
        out[(size_t)node * 2 + 0] = p0 + b[0];
        out[(size_t)node * 2 + 1] = p1 + b[1];
    }
}

extern "C" void kernel_launch(void* const* d_in, const int* in_sizes, int n_in,
                              void* d_out, int out_size, void* d_ws, size_t ws_size,
                              hipStream_t stream)
{
    const float* des   = (const float*)d_in[0];
    const float* tweet = (const float*)d_in[1];
    const float* num   = (const float*)d_in[2];
    const float* cat   = (const float*)d_in[3];
    const int*   eidx  = (const int*)d_in[4];
    const float* W_des = (const float*)d_in[5];  const float* b_des = (const float*)d_in[6];
    const float* W_tw  = (const float*)d_in[7];  const float* b_tw  = (const float*)d_in[8];
    const float* W_num = (const float*)d_in[9];  const float* b_num = (const float*)d_in[10];
    const float* W_cat = (const float*)d_in[11]; const float* b_cat = (const float*)d_in[12];
    const float* W_in  = (const float*)d_in[13]; const float* b_in  = (const float*)d_in[14];
    const float* W_g1  = (const float*)d_in[15]; const float* b_g1  = (const float*)d_in[16];
    const float* W_g2  = (const float*)d_in[17]; const float* b_g2  = (const float*)d_in[18];
    const float* W_o1  = (const float*)d_in[19]; const float* b_o1  = (const float*)d_in[20];
    const float* W_o2  = (const float*)d_in[21]; const float* b_o2  = (const float*)d_in[22];
    float* out = (float*)d_out;

    const int N = in_sizes[0] / 768;
    const int E = in_sizes[4] / 2;
    const int* src = eidx;
    const int* dst = eidx + E;

    // workspace layout
    char* ws = (char*)d_ws;
    const size_t szF = (size_t)N * HID * sizeof(float);
    float* F0 = (float*)ws;                    ws += szF;
    float* F1 = (float*)ws;                    ws += szF;
    float* F2 = (float*)ws;                    ws += szF;
    int* cnt      = (int*)ws;                  ws += ((size_t)N * 4 + 255) & ~255ULL;
    int* row_ptr  = (int*)ws;                  ws += (((size_t)N + 1) * 4 + 255) & ~255ULL;
    int* cursor   = (int*)ws;                  ws += ((size_t)N * 4 + 255) & ~255ULL;
    int* part     = (int*)ws;                  ws += 4096;
    float* dinv   = (float*)ws;                ws += ((size_t)N * 4 + 255) & ~255ULL;
    int* col_idx  = (int*)ws;                  ws += (size_t)E * 4;

    const int B = (N + 255) / 256;  // scan blocks (<= 512)

    // ---- CSR build ----
    hipMemsetAsync(cnt, 0, (size_t)N * sizeof(int), stream);
    hist_kernel<<<1024, 256, 0, stream>>>(dst, cnt, E);
    scan_block_kernel<<<B, 256, 0, stream>>>(cnt, row_ptr, part, N);
    scan_part_kernel<<<1, 512, 0, stream>>>(part, B);
    scan_final_kernel<<<(N + 256) / 256 + 1, 256, 0, stream>>>(row_ptr, part, cursor, cnt, dinv, N, B);
    {
        const int NPART = 2;
        int step = (N + NPART - 1) / NPART;
        for (int p = 0; p < NPART; ++p) {
            int lo = p * step;
            int hi = (lo + step < N) ? lo + step : N;
            scatter_kernel<<<1024, 256, 0, stream>>>(src, dst, cursor, col_idx, E, lo, hi);
        }
    }

    // ---- encoder -> F0 ----
    {
        dim3 grid((N + ENC_BN - 1) / ENC_BN, 2);
        enc_gemm_kernel<<<grid, 512, 0, stream>>>(des, tweet, W_des, b_des, W_tw, b_tw, F0, N);
        enc_nc_kernel<<<((size_t)N * 64 + 255) / 256, 256, 0, stream>>>(num, cat, W_num, b_num, W_cat, b_cat, F0, N);
    }

    int ggrid = (N + 127) / 128;
    int cgrid = (int)(((size_t)N * 32 + 255) / 256);

    // ---- x1 = lrelu(x0 @ W_in + b_in) -> F1 (f32) ----
    gemm128_kernel<true, true, false, false><<<ggrid, 512, 0, stream>>>(F0, W_in, b_in, nullptr, F1, N);

    // ---- conv1: hs1 = (x1 @ W_g1) * dinv -> F2 (bf16) ; c1 -> F0 (f32) ----
    gemm128_kernel<false, false, true, true><<<ggrid, 512, 0, stream>>>(F1, W_g1, nullptr, dinv, F2, N);
    conv_gather_bf16_kernel<<<cgrid, 256, 0, stream>>>((const unsigned*)F2, row_ptr, col_idx, dinv, b_g1, F0, N);

    // ---- conv2: hs2 = (c1 @ W_g2) * dinv -> F1 (bf16) ; c2 -> F2 (f32) ----
    gemm128_kernel<false, false, true, true><<<ggrid, 512, 0, stream>>>(F0, W_g2, nullptr, dinv, F1, N);
    conv_gather_bf16_kernel<<<cgrid, 256, 0, stream>>>((const unsigned*)F1, row_ptr, col_idx, dinv, b_g2, F2, N);

    // ---- y = lrelu(c2 @ W_o1 + b_o1) -> F0 (f32) ----
    gemm128_kernel<true, true, false, false><<<ggrid, 512, 0, stream>>>(F2, W_o1, b_o1, nullptr, F0, N);

    // ---- out = y @ W_o2 + b_o2 ----
    out_kernel<<<((size_t)N * 64 + 255) / 256, 256, 0, stream>>>(F0, W_o2, b_o2, out, N);
}

// Round 8
// 1019.887 us; speedup vs baseline: 1.0967x; 1.0967x over previous
//
#include <hip/hip_runtime.h>
#include <hip/hip_bf16.h>
#include <cstdint>

#define HID 128

typedef short short8 __attribute__((ext_vector_type(8)));
typedef float f32x4 __attribute__((ext_vector_type(4)));

__device__ __forceinline__ unsigned pack_bf16(float a, float b)
{
    __hip_bfloat16 ha = __float2bfloat16(a);
    __hip_bfloat16 hb = __float2bfloat16(b);
    unsigned short ua = *reinterpret_cast<unsigned short*>(&ha);
    unsigned short ub = *reinterpret_cast<unsigned short*>(&hb);
    return (unsigned)ua | ((unsigned)ub << 16);
}

__device__ __forceinline__ float bf16_lo(unsigned u)
{
    unsigned v = u << 16;
    return *reinterpret_cast<float*>(&v);
}
__device__ __forceinline__ float bf16_hi(unsigned u)
{
    unsigned v = u & 0xffff0000u;
    return *reinterpret_cast<float*>(&v);
}

// truncate-split: x = hi + lo, both bf16-representable (err ~2^-16 rel)
__device__ __forceinline__ void split_bf16(float x, unsigned short& hi, unsigned short& lo)
{
    unsigned bits = __float_as_uint(x);
    hi = (unsigned short)(bits >> 16);
    unsigned hb = bits & 0xffff0000u;
    float lof = x - *reinterpret_cast<float*>(&hb);
    lo = (unsigned short)(__float_as_uint(lof) >> 16);
}

// ---------------------------------------------------------------------------
// Encoder GEMM via split-bf16 MFMA: [N,768] @ [768,32], des (y=0)/tweet (y=1).
// Block: 512 threads (8 waves) -> 256 nodes x 32 cols. K-chunk 32.
// LDS holds A and W chunks in MFMA FRAGMENT ORDER: [tile][lane][8 bf16],
// so fragment loads are lane-linear ds_read_b128 (conflict-free).
// A frag: row=lane&15, k=(lane>>4)*8+j.  B frag: col=lane&15, same k.
// C/D: col=lane&15, row=(lane>>4)*4+reg (m89-verified).
// 3-term split: acc += Ah*Wh + Ah*Wl + Al*Wh.
// ---------------------------------------------------------------------------
#define ENC_BN 256

__global__ __launch_bounds__(512, 4) void enc_mfma_kernel(
    const float* __restrict__ des, const float* __restrict__ tweet,
    const float* __restrict__ Wd, const float* __restrict__ bd,
    const float* __restrict__ Wt, const float* __restrict__ bt,
    float* __restrict__ x0, int N)
{
    __shared__ short A_hi[16][64][8];   // 16 m_tiles x 64 lanes x 8 bf16 = 16KB
    __shared__ short A_lo[16][64][8];
    __shared__ short W_hi[2][64][8];    // 2 n_tiles
    __shared__ short W_lo[2][64][8];

    const int mat = blockIdx.y;
    const float* __restrict__ X = mat ? tweet : des;
    const float* __restrict__ W = mat ? Wt : Wd;
    const float* __restrict__ B = mat ? bt : bd;
    const int n0 = blockIdx.x * ENC_BN;
    const int t = threadIdx.x;          // 0..511
    const int lane = t & 63;
    const int wv = t >> 6;              // wave 0..7, owns m_tiles {2wv, 2wv+1}

    // A staging coords: thread covers nodes rbase+64*i (i<4), k-quad f4
    const int f4 = t & 7;
    const int rbase = t >> 3;           // 0..63
    const int a_lane = (rbase & 15) + 16 * (f4 >> 1);   // frag lane for these elems
    const int a_off = (f4 & 1) * 4;                     // elem offset (bf16 units)

    // W staging coords (t<256): c = t&31, kq = t>>5 (k = kq*4..+3)
    const int wc = t & 31;
    const int wkq = (t >> 5) & 7;
    const int w_lane = (wc & 15) + 16 * (wkq >> 1);
    const int w_off = (wkq & 1) * 4;
    const int w_nt = wc >> 4;

    f32x4 acc[2][2] = {};

    float4 preA[4];
    float preWv[4];

    // prologue: prefetch chunk 0
    #pragma unroll
    for (int i = 0; i < 4; ++i) {
        int node = n0 + rbase + 64 * i;
        preA[i] = make_float4(0.f, 0.f, 0.f, 0.f);
        if (node < N)
            preA[i] = *reinterpret_cast<const float4*>(X + (size_t)node * 768 + f4 * 4);
    }
    if (t < 256) {
        #pragma unroll
        for (int r = 0; r < 4; ++r)
            preWv[r] = W[(size_t)(wkq * 4 + r) * 32 + wc];
    }

    for (int k0 = 0; k0 < 768; k0 += 32) {
        // ---- stage A (split hi/lo, fragment order) ----
        #pragma unroll
        for (int i = 0; i < 4; ++i) {
            int mt = (rbase >> 4) + 4 * i;        // node>>4 for node=rbase+64i
            unsigned short h0, h1, h2, h3, l0, l1, l2, l3;
            split_bf16(preA[i].x, h0, l0);
            split_bf16(preA[i].y, h1, l1);
            split_bf16(preA[i].z, h2, l2);
            split_bf16(preA[i].w, h3, l3);
            uint2 hu = make_uint2((unsigned)h0 | ((unsigned)h1 << 16),
                                  (unsigned)h2 | ((unsigned)h3 << 16));
            uint2 lu = make_uint2((unsigned)l0 | ((unsigned)l1 << 16),
                                  (unsigned)l2 | ((unsigned)l3 << 16));
            *reinterpret_cast<uint2*>(&A_hi[mt][a_lane][a_off]) = hu;
            *reinterpret_cast<uint2*>(&A_lo[mt][a_lane][a_off]) = lu;
        }
        // ---- stage W ----
        if (t < 256) {
            unsigned short h0, h1, h2, h3, l0, l1, l2, l3;
            split_bf16(preWv[0], h0, l0);
            split_bf16(preWv[1], h1, l1);
            split_bf16(preWv[2], h2, l2);
            split_bf16(preWv[3], h3, l3);
            uint2 hu = make_uint2((unsigned)h0 | ((unsigned)h1 << 16),
                                  (unsigned)h2 | ((unsigned)h3 << 16));
            uint2 lu = make_uint2((unsigned)l0 | ((unsigned)l1 << 16),
                                  (unsigned)l2 | ((unsigned)l3 << 16));
            *reinterpret_cast<uint2*>(&W_hi[w_nt][w_lane][w_off]) = hu;
            *reinterpret_cast<uint2*>(&W_lo[w_nt][w_lane][w_off]) = lu;
        }
        __syncthreads();

        // ---- prefetch next chunk (hides under MFMA) ----
        int k1 = k0 + 32;
        if (k1 < 768) {
            #pragma unroll
            for (int i = 0; i < 4; ++i) {
                int node = n0 + rbase + 64 * i;
                preA[i] = make_float4(0.f, 0.f, 0.f, 0.f);
                if (node < N)
                    preA[i] = *reinterpret_cast<const float4*>(X + (size_t)node * 768 + k1 + f4 * 4);
            }
            if (t < 256) {
                #pragma unroll
                for (int r = 0; r < 4; ++r)
                    preWv[r] = W[(size_t)(k1 + wkq * 4 + r) * 32 + wc];
            }
        }

        // ---- MFMA phase ----
        short8 ah0 = *reinterpret_cast<short8*>(&A_hi[2 * wv + 0][lane][0]);
        short8 ah1 = *reinterpret_cast<short8*>(&A_hi[2 * wv + 1][lane][0]);
        short8 al0 = *reinterpret_cast<short8*>(&A_lo[2 * wv + 0][lane][0]);
        short8 al1 = *reinterpret_cast<short8*>(&A_lo[2 * wv + 1][lane][0]);
        short8 wh0 = *reinterpret_cast<short8*>(&W_hi[0][lane][0]);
        short8 wh1 = *reinterpret_cast<short8*>(&W_hi[1][lane][0]);
        short8 wl0 = *reinterpret_cast<short8*>(&W_lo[0][lane][0]);
        short8 wl1 = *reinterpret_cast<short8*>(&W_lo[1][lane][0]);

        acc[0][0] = __builtin_amdgcn_mfma_f32_16x16x32_bf16(ah0, wh0, acc[0][0], 0, 0, 0);
        acc[0][1] = __builtin_amdgcn_mfma_f32_16x16x32_bf16(ah0, wh1, acc[0][1], 0, 0, 0);
        acc[1][0] = __builtin_amdgcn_mfma_f32_16x16x32_bf16(ah1, wh0, acc[1][0], 0, 0, 0);
        acc[1][1] = __builtin_amdgcn_mfma_f32_16x16x32_bf16(ah1, wh1, acc[1][1], 0, 0, 0);
        acc[0][0] = __builtin_amdgcn_mfma_f32_16x16x32_bf16(ah0, wl0, acc[0][0], 0, 0, 0);
        acc[0][1] = __builtin_amdgcn_mfma_f32_16x16x32_bf16(ah0, wl1, acc[0][1], 0, 0, 0);
        acc[1][0] = __builtin_amdgcn_mfma_f32_16x16x32_bf16(ah1, wl0, acc[1][0], 0, 0, 0);
        acc[1][1] = __builtin_amdgcn_mfma_f32_16x16x32_bf16(ah1, wl1, acc[1][1], 0, 0, 0);
        acc[0][0] = __builtin_amdgcn_mfma_f32_16x16x32_bf16(al0, wh0, acc[0][0], 0, 0, 0);
        acc[0][1] = __builtin_amdgcn_mfma_f32_16x16x32_bf16(al0, wh1, acc[0][1], 0, 0, 0);
        acc[1][0] = __builtin_amdgcn_mfma_f32_16x16x32_bf16(al1, wh0, acc[1][0], 0, 0, 0);
        acc[1][1] = __builtin_amdgcn_mfma_f32_16x16x32_bf16(al1, wh1, acc[1][1], 0, 0, 0);
        __syncthreads();
    }

    // ---- epilogue: bias + lrelu + store ----
    #pragma unroll
    for (int mt = 0; mt < 2; ++mt) {
        #pragma unroll
        for (int nt = 0; nt < 2; ++nt) {
            int col_local = nt * 16 + (lane & 15);
            float bias = B[col_local];
            #pragma unroll
            for (int r = 0; r < 4; ++r) {
                int node = n0 + (2 * wv + mt) * 16 + (lane >> 4) * 4 + r;
                if (node < N) {
                    float v = acc[mt][nt][r] + bias;
                    v = v > 0.f ? v : 0.01f * v;
                    x0[(size_t)node * HID + mat * 32 + col_local] = v;
                }
            }
        }
    }
}

// x0[:,64:96] = lrelu(num @ W_num + b), x0[:,96:128] = lrelu(cat @ W_cat + b)
__global__ void enc_nc_kernel(const float* __restrict__ num, const float* __restrict__ cat,
                              const float* __restrict__ Wn, const float* __restrict__ bn,
                              const float* __restrict__ Wc, const float* __restrict__ bc,
                              float* __restrict__ x0, int N)
{
    int tid = blockIdx.x * blockDim.x + threadIdx.x;
    int col = tid & 63;
    int node = tid >> 6;
    if (node >= N) return;
    float a;
    if (col < 32) {
        const float* r = num + (size_t)node * 5;
        float acc = bn[col];
        #pragma unroll
        for (int k = 0; k < 5; ++k) acc = fmaf(r[k], Wn[k * 32 + col], acc);
        a = acc;
    } else {
        int c = col & 31;
        a = fmaf(cat[node], Wc[c], bc[c]);
    }
    a = a > 0.f ? a : 0.01f * a;
    x0[(size_t)node * HID + 64 + col] = a;
}

// ---------------------------------------------------------------------------
// Dense [N,128] @ [128,128]. Block: 512 threads -> 128 nodes x 128 cols.
// Register-prefetch double buffering. BF16OUT for conv feeds. (R7 structure)
// ---------------------------------------------------------------------------
template<bool BIAS, bool LRELU, bool DINV, bool BF16OUT>
__global__ __launch_bounds__(512, 4) void gemm128_kernel(
    const float* __restrict__ in, const float* __restrict__ W,
    const float* __restrict__ b, const float* __restrict__ dinv,
    void* __restrict__ outp, int N)
{
    __shared__ float At[32][128];   // XOR-swizzled cols
    __shared__ float Wl[32][128];
    const int n0 = blockIdx.x * 128;
    const int t = threadIdx.x;      // 0..511
    const int cg = t & 15;          // cols {cg*4, 64+cg*4}
    const int ng = t >> 4;          // 0..31, 4 nodes each

    float acc[4][8] = {};

    const int f4 = t & 7;
    const int rbase = t >> 3;       // 0..63
    const int sw = 4 * f4;
    const int wf = t & 31;
    const int kk = t >> 5;          // 0..15

    float4 preA[2], preW[2];
    #pragma unroll
    for (int i = 0; i < 2; ++i) {
        int node = n0 + rbase + 64 * i;
        preA[i] = make_float4(0.f, 0.f, 0.f, 0.f);
        if (node < N)
            preA[i] = *reinterpret_cast<const float4*>(in + (size_t)node * HID + f4 * 4);
        preW[i] = *reinterpret_cast<const float4*>(W + (size_t)(kk + 16 * i) * HID + wf * 4);
    }

    for (int k0 = 0; k0 < 128; k0 += 32) {
        #pragma unroll
        for (int i = 0; i < 2; ++i) {
            int row = rbase + 64 * i;
            int colw = row ^ sw;
            At[f4 * 4 + 0][colw] = preA[i].x;
            At[f4 * 4 + 1][colw] = preA[i].y;
            At[f4 * 4 + 2][colw] = preA[i].z;
            At[f4 * 4 + 3][colw] = preA[i].w;
            *reinterpret_cast<float4*>(&Wl[kk + 16 * i][wf * 4]) = preW[i];
        }
        __syncthreads();

        int k1 = k0 + 32;
        if (k1 < 128) {
            #pragma unroll
            for (int i = 0; i < 2; ++i) {
                int node = n0 + rbase + 64 * i;
                preA[i] = make_float4(0.f, 0.f, 0.f, 0.f);
                if (node < N)
                    preA[i] = *reinterpret_cast<const float4*>(in + (size_t)node * HID + k1 + f4 * 4);
                preW[i] = *reinterpret_cast<const float4*>(W + (size_t)(k1 + kk + 16 * i) * HID + wf * 4);
            }
        }

        #pragma unroll
        for (int k = 0; k < 32; ++k) {
            int fk = 4 * ((k >> 2) & 7);
            int c0 = (ng * 4) ^ fk;
            float4 a  = *reinterpret_cast<const float4*>(&At[k][c0]);
            float4 w0 = *reinterpret_cast<const float4*>(&Wl[k][cg * 4]);
            float4 w1 = *reinterpret_cast<const float4*>(&Wl[k][64 + cg * 4]);
            float av[4] = {a.x, a.y, a.z, a.w};
            float wc[8] = {w0.x, w0.y, w0.z, w0.w, w1.x, w1.y, w1.z, w1.w};
            #pragma unroll
            for (int j = 0; j < 4; ++j)
                #pragma unroll
                for (int c = 0; c < 8; ++c)
                    acc[j][c] = fmaf(av[j], wc[c], acc[j][c]);
        }
        __syncthreads();
    }

    float bc[8];
    if (BIAS) {
        float4 b0 = *reinterpret_cast<const float4*>(b + cg * 4);
        float4 b1 = *reinterpret_cast<const float4*>(b + 64 + cg * 4);
        bc[0]=b0.x; bc[1]=b0.y; bc[2]=b0.z; bc[3]=b0.w;
        bc[4]=b1.x; bc[5]=b1.y; bc[6]=b1.z; bc[7]=b1.w;
    }
    #pragma unroll
    for (int j = 0; j < 4; ++j) {
        int node = n0 + ng * 4 + j;
        if (node >= N) break;
        float di;
        if (DINV) di = dinv[node];
        float o[8];
        #pragma unroll
        for (int c = 0; c < 8; ++c) {
            float a = acc[j][c];
            if (BIAS)  a += bc[c];
            if (LRELU) a = a > 0.f ? a : 0.01f * a;
            if (DINV)  a *= di;
            o[c] = a;
        }
        if (BF16OUT) {
            unsigned* row = reinterpret_cast<unsigned*>(outp) + (size_t)node * (HID / 2);
            uint2 s0 = make_uint2(pack_bf16(o[0], o[1]), pack_bf16(o[2], o[3]));
            uint2 s1 = make_uint2(pack_bf16(o[4], o[5]), pack_bf16(o[6], o[7]));
            *reinterpret_cast<uint2*>(row + cg * 2)      = s0;
            *reinterpret_cast<uint2*>(row + 32 + cg * 2) = s1;
        } else {
            float* out = reinterpret_cast<float*>(outp);
            float4 s0 = make_float4(o[0], o[1], o[2], o[3]);
            float4 s1 = make_float4(o[4], o[5], o[6], o[7]);
            *reinterpret_cast<float4*>(out + (size_t)node * HID + cg * 4)      = s0;
            *reinterpret_cast<float4*>(out + (size_t)node * HID + 64 + cg * 4) = s1;
        }
    }
}

// ---------------------------------------------------------------------------
// CSR build: histogram -> exclusive scan -> range-partitioned scatter
// ---------------------------------------------------------------------------
__global__ void hist_kernel(const int* __restrict__ dst, int* __restrict__ cnt, int E)
{
    int i = blockIdx.x * blockDim.x + threadIdx.x;
    int stride = gridDim.x * blockDim.x;
    for (; i < E; i += stride) atomicAdd(&cnt[dst[i]], 1);
}

__global__ void scan_block_kernel(const int* __restrict__ cnt, int* __restrict__ excl_out,
                                  int* __restrict__ part, int N)
{
    __shared__ int s[256];
    int t = threadIdx.x;
    int i = blockIdx.x * 256 + t;
    int v = (i < N) ? cnt[i] : 0;
    s[t] = v;
    __syncthreads();
    #pragma unroll
    for (int off = 1; off < 256; off <<= 1) {
        int x = (t >= off) ? s[t - off] : 0;
        __syncthreads();
        s[t] += x;
        __syncthreads();
    }
    int incl = s[t];
    if (i < N) excl_out[i] = incl - v;
    if (t == 255) part[blockIdx.x] = incl;
}

__global__ void scan_part_kernel(int* __restrict__ part, int B)
{
    __shared__ int s[512];
    int t = threadIdx.x;
    int v = (t < B) ? part[t] : 0;
    s[t] = v;
    __syncthreads();
    #pragma unroll
    for (int off = 1; off < 512; off <<= 1) {
        int x = (t >= off) ? s[t - off] : 0;
        __syncthreads();
        s[t] += x;
        __syncthreads();
    }
    int incl = s[t];
    if (t < B) part[t] = incl - v;
    if (t == B - 1) part[B] = incl;
}

__global__ void scan_final_kernel(int* __restrict__ row_ptr, const int* __restrict__ part,
                                  int* __restrict__ cursor, const int* __restrict__ cnt,
                                  float* __restrict__ dinv, int N, int B)
{
    int i = blockIdx.x * blockDim.x + threadIdx.x;
    if (i < N) {
        int rp = row_ptr[i] + part[i >> 8];
        row_ptr[i] = rp;
        cursor[i] = rp;
        dinv[i] = rsqrtf((float)(cnt[i] + 1));
    } else if (i == N) {
        row_ptr[N] = part[B];
    }
}

__global__ void scatter_kernel(const int* __restrict__ src, const int* __restrict__ dst,
                               int* __restrict__ cursor, int* __restrict__ col_idx,
                               int E, int lo, int hi)
{
    int i = blockIdx.x * blockDim.x + threadIdx.x;
    int stride = gridDim.x * blockDim.x;
    for (; i < E; i += stride) {
        int d = dst[i];
        if (d >= lo && d < hi) {
            int pos = atomicAdd(&cursor[d], 1);
            col_idx[pos] = src[i];
        }
    }
}

// ---------------------------------------------------------------------------
// GCN gather (bf16 hs): out[i] = dinv[i] * (hs[i] + sum hs[src]) + b
// ---------------------------------------------------------------------------
__global__ void conv_gather_bf16_kernel(const unsigned* __restrict__ hs,
                                        const int* __restrict__ row_ptr,
                                        const int* __restrict__ col_idx,
                                        const float* __restrict__ dinv,
                                        const float* __restrict__ b,
                                        float* __restrict__ out, int N)
{
    int tid = blockIdx.x * blockDim.x + threadIdx.x;
    int node = tid >> 5;
    int f4 = tid & 31;
    if (node >= N) return;
    const uint2* base = reinterpret_cast<const uint2*>(hs);
    float a0, a1, a2, a3;
    {
        uint2 v = base[(size_t)node * 32 + f4];
        a0 = bf16_lo(v.x); a1 = bf16_hi(v.x);
        a2 = bf16_lo(v.y); a3 = bf16_hi(v.y);
    }
    int e = row_ptr[node], end = row_ptr[node + 1];
    while (e < end) {
        int m = end - e;
        if (m >= 32) {
            int idx = col_idx[e + f4];
            #pragma unroll 8
            for (int j = 0; j < 32; ++j) {
                int s = __shfl(idx, j, 32);
                uint2 v = base[(size_t)s * 32 + f4];
                a0 += bf16_lo(v.x); a1 += bf16_hi(v.x);
                a2 += bf16_lo(v.y); a3 += bf16_hi(v.y);
            }
            e += 32;
        } else {
            int idx = (f4 < m) ? col_idx[e + f4] : 0;
            for (int j = 0; j < m; ++j) {
                int s = __shfl(idx, j, 32);
                uint2 v = base[(size_t)s * 32 + f4];
                a0 += bf16_lo(v.x); a1 += bf16_hi(v.x);
                a2 += bf16_lo(v.y); a3 += bf16_hi(v.y);
            }
            e = end;
        }
    }
    float di = dinv[node];
    float4 b4 = reinterpret_cast<const float4*>(b)[f4];
    float4 o;
    o.x = fmaf(di, a0, b4.x);
    o.y = fmaf(di, a1, b4.y);
    o.z = fmaf(di, a2, b4.z);
    o.w = fmaf(di, a3, b4.w);
    reinterpret_cast<float4*>(out)[(size_t)node * 32 + f4] = o;
}

// ---------------------------------------------------------------------------
// Final: out[n,0:2] = y[n] @ W_o2 + b_o2. One wave per node.
// ---------------------------------------------------------------------------
__global__ void out_kernel(const float* __restrict__ y, const float* __restrict__ W,
                           const float* __restrict__ b, float* __restrict__ out, int N)
{
    int tid = blockIdx.x * blockDim.x + threadIdx.x;
    int lane = tid & 63;
    int node = tid >> 6;
    if (node >= N) return;
    const float* r = y + (size_t)node * HID;
    float v0 = r[lane], v1 = r[lane + 64];
    float p0 = v0 * W[lane * 2 + 0] + v1 * W[(lane + 64) * 2 + 0];
    float p1 = v0 * W[lane * 2 + 1] + v1 * W[(lane + 64) * 2 + 1];
    #pragma unroll
    for (int off = 32; off; off >>= 1) {
        p0 += __shfl_down(p0, off);
        p1 += __shfl_down(p1, off);
    }
    if (lane == 0) {
        out[(size_t)node * 2 + 0] = p0 + b[0];
        out[(size_t)node * 2 + 1] = p1 + b[1];
    }
}

extern "C" void kernel_launch(void* const* d_in, const int* in_sizes, int n_in,
                              void* d_out, int out_size, void* d_ws, size_t ws_size,
                              hipStream_t stream)
{
    const float* des   = (const float*)d_in[0];
    const float* tweet = (const float*)d_in[1];
    const float* num   = (const float*)d_in[2];
    const float* cat   = (const float*)d_in[3];
    const int*   eidx  = (const int*)d_in[4];
    const float* W_des = (const float*)d_in[5];  const float* b_des = (const float*)d_in[6];
    const float* W_tw  = (const float*)d_in[7];  const float* b_tw  = (const float*)d_in[8];
    const float* W_num = (const float*)d_in[9];  const float* b_num = (const float*)d_in[10];
    const float* W_cat = (const float*)d_in[11]; const float* b_cat = (const float*)d_in[12];
    const float* W_in  = (const float*)d_in[13]; const float* b_in  = (const float*)d_in[14];
    const float* W_g1  = (const float*)d_in[15]; const float* b_g1  = (const float*)d_in[16];
    const float* W_g2  = (const float*)d_in[17]; const float* b_g2  = (const float*)d_in[18];
    const float* W_o1  = (const float*)d_in[19]; const float* b_o1  = (const float*)d_in[20];
    const float* W_o2  = (const float*)d_in[21]; const float* b_o2  = (const float*)d_in[22];
    float* out = (float*)d_out;

    const int N = in_sizes[0] / 768;
    const int E = in_sizes[4] / 2;
    const int* src = eidx;
    const int* dst = eidx + E;

    // workspace layout
    char* ws = (char*)d_ws;
    const size_t szF = (size_t)N * HID * sizeof(float);
    float* F0 = (float*)ws;                    ws += szF;
    float* F1 = (float*)ws;                    ws += szF;
    float* F2 = (float*)ws;                    ws += szF;
    int* cnt      = (int*)ws;                  ws += ((size_t)N * 4 + 255) & ~255ULL;
    int* row_ptr  = (int*)ws;                  ws += (((size_t)N + 1) * 4 + 255) & ~255ULL;
    int* cursor   = (int*)ws;                  ws += ((size_t)N * 4 + 255) & ~255ULL;
    int* part     = (int*)ws;                  ws += 4096;
    float* dinv   = (float*)ws;                ws += ((size_t)N * 4 + 255) & ~255ULL;
    int* col_idx  = (int*)ws;                  ws += (size_t)E * 4;

    const int B = (N + 255) / 256;  // scan blocks (<= 512)

    // ---- CSR build ----
    hipMemsetAsync(cnt, 0, (size_t)N * sizeof(int), stream);
    hist_kernel<<<1024, 256, 0, stream>>>(dst, cnt, E);
    scan_block_kernel<<<B, 256, 0, stream>>>(cnt, row_ptr, part, N);
    scan_part_kernel<<<1, 512, 0, stream>>>(part, B);
    scan_final_kernel<<<(N + 256) / 256 + 1, 256, 0, stream>>>(row_ptr, part, cursor, cnt, dinv, N, B);
    {
        const int NPART = 4;
        int step = (N + NPART - 1) / NPART;
        for (int p = 0; p < NPART; ++p) {
            int lo = p * step;
            int hi = (lo + step < N) ? lo + step : N;
            scatter_kernel<<<1024, 256, 0, stream>>>(src, dst, cursor, col_idx, E, lo, hi);
        }
    }

    // ---- encoder -> F0 ----
    {
        dim3 grid((N + ENC_BN - 1) / ENC_BN, 2);
        enc_mfma_kernel<<<grid, 512, 0, stream>>>(des, tweet, W_des, b_des, W_tw, b_tw, F0, N);
        enc_nc_kernel<<<((size_t)N * 64 + 255) / 256, 256, 0, stream>>>(num, cat, W_num, b_num, W_cat, b_cat, F0, N);
    }

    int ggrid = (N + 127) / 128;
    int cgrid = (int)(((size_t)N * 32 + 255) / 256);

    // ---- x1 = lrelu(x0 @ W_in + b_in) -> F1 (f32) ----
    gemm128_kernel<true, true, false, false><<<ggrid, 512, 0, stream>>>(F0, W_in, b_in, nullptr, F1, N);

    // ---- conv1: hs1 = (x1 @ W_g1) * dinv -> F2 (bf16) ; c1 -> F0 (f32) ----
    gemm128_kernel<false, false, true, true><<<ggrid, 512, 0, stream>>>(F1, W_g1, nullptr, dinv, F2, N);
    conv_gather_bf16_kernel<<<cgrid, 256, 0, stream>>>((const unsigned*)F2, row_ptr, col_idx, dinv, b_g1, F0, N);

    // ---- conv2: hs2 = (c1 @ W_g2) * dinv -> F1 (bf16) ; c2 -> F2 (f32) ----
    gemm128_kernel<false, false, true, true><<<ggrid, 512, 0, stream>>>(F0, W_g2, nullptr, dinv, F1, N);
    conv_gather_bf16_kernel<<<cgrid, 256, 0, stream>>>((const unsigned*)F1, row_ptr, col_idx, dinv, b_g2, F2, N);

    // ---- y = lrelu(c2 @ W_o1 + b_o1) -> F0 (f32) ----
    gemm128_kernel<true, true, false, false><<<ggrid, 512, 0, stream>>>(F2, W_o1, b_o1, nullptr, F0, N);

    // ---- out = y @ W_o2 + b_o2 ----
    out_kernel<<<((size_t)N * 64 + 255) / 256, 256, 0, stream>>>(F0, W_o2, b_o2, out, N);
}

// Round 9
// 909.610 us; speedup vs baseline: 1.2297x; 1.1212x over previous
//
#include <hip/hip_runtime.h>
#include <hip/hip_bf16.h>
#include <cstdint>

#define HID 128

typedef short short8 __attribute__((ext_vector_type(8)));
typedef float f32x4 __attribute__((ext_vector_type(4)));

__device__ __forceinline__ unsigned pack_bf16(float a, float b)
{
    __hip_bfloat16 ha = __float2bfloat16(a);
    __hip_bfloat16 hb = __float2bfloat16(b);
    unsigned short ua = *reinterpret_cast<unsigned short*>(&ha);
    unsigned short ub = *reinterpret_cast<unsigned short*>(&hb);
    return (unsigned)ua | ((unsigned)ub << 16);
}

__device__ __forceinline__ float bf16_lo(unsigned u)
{
    unsigned v = u << 16;
    return *reinterpret_cast<float*>(&v);
}
__device__ __forceinline__ float bf16_hi(unsigned u)
{
    unsigned v = u & 0xffff0000u;
    return *reinterpret_cast<float*>(&v);
}

// truncate-split x = hi + lo (both bf16-representable), for 8 values
__device__ __forceinline__ void split8(const float* v, short8& h, short8& l)
{
    #pragma unroll
    for (int j = 0; j < 8; ++j) {
        unsigned bits = __float_as_uint(v[j]);
        h[j] = (short)(bits >> 16);
        unsigned hb = bits & 0xffff0000u;
        float lof = v[j] - __uint_as_float(hb);
        l[j] = (short)(__float_as_uint(lof) >> 16);
    }
}

// fragment array layout: frag row index = (kc*NT + nt)*64 + lane, 8 bf16 each.
// W frag (B-operand): col = nt*16 + (lane&15), k = kc*32 + ((lane>>4)&3)*8 + j.
__device__ __forceinline__ short8 frag_ld(const short* __restrict__ base, int tile, int lane)
{
    return *reinterpret_cast<const short8*>(base + (((size_t)tile * 64 + lane) << 3));
}

// ---------------------------------------------------------------------------
// One-shot weight conversion: f32 [K][C] -> fragment-ordered bf16 hi/lo.
// job 0/1: K=768,C=32 (W_des/W_tweet); jobs 2..5: K=128,C=128.
// ---------------------------------------------------------------------------
__global__ void convert_w_kernel(
    const float* W0, const float* W1, const float* W2,
    const float* W3, const float* W4, const float* W5,
    short* H0, short* L0, short* H1, short* L1, short* H2, short* L2,
    short* H3, short* L3, short* H4, short* L4, short* H5, short* L5)
{
    int job = blockIdx.y;
    const float* W; short* H; short* L; int K, C;
    switch (job) {
        case 0: W = W0; H = H0; L = L0; K = 768; C = 32;  break;
        case 1: W = W1; H = H1; L = L1; K = 768; C = 32;  break;
        case 2: W = W2; H = H2; L = L2; K = 128; C = 128; break;
        case 3: W = W3; H = H3; L = L3; K = 128; C = 128; break;
        case 4: W = W4; H = H4; L = L4; K = 128; C = 128; break;
        default: W = W5; H = H5; L = L5; K = 128; C = 128; break;
    }
    int NT = C >> 4;
    int rows = (K >> 5) * NT * 64;
    int r = blockIdx.x * blockDim.x + threadIdx.x;
    if (r >= rows) return;
    int lane = r & 63;
    int tile = r >> 6;              // kc*NT + nt
    int c = (tile % NT) * 16 + (lane & 15);
    int kbase = (tile / NT) * 32 + ((lane >> 4) & 3) * 8;
    float v[8];
    #pragma unroll
    for (int j = 0; j < 8; ++j) v[j] = W[(size_t)(kbase + j) * C + c];
    short8 h, l;
    split8(v, h, l);
    *reinterpret_cast<short8*>(H + ((size_t)r << 3)) = h;
    *reinterpret_cast<short8*>(L + ((size_t)r << 3)) = l;
}

// ---------------------------------------------------------------------------
// Encoder [N,768]@[768,32] via LDS-free, barrier-free split-bf16 MFMA.
// Block 256 thr (4 waves); wave = 16 nodes x 32 cols; A frags loaded straight
// from global (8 contiguous f32 per lane), W frags from converted arrays.
// acc rows: node=(lane>>4)*4+r, col=lane&15 (m89-verified C/D layout).
// ---------------------------------------------------------------------------
__global__ __launch_bounds__(256, 4) void enc_mfma2_kernel(
    const float* __restrict__ des, const float* __restrict__ tweet,
    const short* __restrict__ wdes_hi, const short* __restrict__ wdes_lo,
    const short* __restrict__ wtw_hi, const short* __restrict__ wtw_lo,
    const float* __restrict__ bd, const float* __restrict__ bt,
    float* __restrict__ x0, int N)
{
    const int mat = blockIdx.y;
    const float* __restrict__ X = mat ? tweet : des;
    const short* __restrict__ WH = mat ? wtw_hi : wdes_hi;
    const short* __restrict__ WL = mat ? wtw_lo : wdes_lo;
    const float* __restrict__ B = mat ? bt : bd;

    const int t = threadIdx.x;
    const int lane = t & 63;
    const int wv = t >> 6;
    const int n0 = blockIdx.x * 64;
    const int arow = n0 + wv * 16 + (lane & 15);
    const bool valid = arow < N;
    const float* __restrict__ ap = X + (size_t)arow * 768 + ((lane >> 4) & 3) * 8;

    f32x4 acc0 = {}, acc1 = {};

    #pragma unroll 2
    for (int kc = 0; kc < 24; ++kc) {
        float av[8] = {};
        if (valid) {
            float4 u0 = *reinterpret_cast<const float4*>(ap + kc * 32);
            float4 u1 = *reinterpret_cast<const float4*>(ap + kc * 32 + 4);
            av[0] = u0.x; av[1] = u0.y; av[2] = u0.z; av[3] = u0.w;
            av[4] = u1.x; av[5] = u1.y; av[6] = u1.z; av[7] = u1.w;
        }
        short8 ah, al;
        split8(av, ah, al);
        short8 wh0 = frag_ld(WH, kc * 2 + 0, lane);
        short8 wl0 = frag_ld(WL, kc * 2 + 0, lane);
        short8 wh1 = frag_ld(WH, kc * 2 + 1, lane);
        short8 wl1 = frag_ld(WL, kc * 2 + 1, lane);
        acc0 = __builtin_amdgcn_mfma_f32_16x16x32_bf16(ah, wh0, acc0, 0, 0, 0);
        acc1 = __builtin_amdgcn_mfma_f32_16x16x32_bf16(ah, wh1, acc1, 0, 0, 0);
        acc0 = __builtin_amdgcn_mfma_f32_16x16x32_bf16(ah, wl0, acc0, 0, 0, 0);
        acc1 = __builtin_amdgcn_mfma_f32_16x16x32_bf16(ah, wl1, acc1, 0, 0, 0);
        acc0 = __builtin_amdgcn_mfma_f32_16x16x32_bf16(al, wh0, acc0, 0, 0, 0);
        acc1 = __builtin_amdgcn_mfma_f32_16x16x32_bf16(al, wh1, acc1, 0, 0, 0);
    }

    const int cl = lane & 15;
    float b0 = B[cl], b1 = B[16 + cl];
    const int nodeb = n0 + wv * 16 + (lane >> 4) * 4;
    #pragma unroll
    for (int r = 0; r < 4; ++r) {
        int node = nodeb + r;
        if (node < N) {
            float v0 = acc0[r] + b0; v0 = v0 > 0.f ? v0 : 0.01f * v0;
            float v1 = acc1[r] + b1; v1 = v1 > 0.f ? v1 : 0.01f * v1;
            x0[(size_t)node * HID + mat * 32 + cl] = v0;
            x0[(size_t)node * HID + mat * 32 + 16 + cl] = v1;
        }
    }
}

// x0[:,64:96] = lrelu(num @ W_num + b), x0[:,96:128] = lrelu(cat @ W_cat + b)
__global__ void enc_nc_kernel(const float* __restrict__ num, const float* __restrict__ cat,
                              const float* __restrict__ Wn, const float* __restrict__ bn,
                              const float* __restrict__ Wc, const float* __restrict__ bc,
                              float* __restrict__ x0, int N)
{
    int tid = blockIdx.x * blockDim.x + threadIdx.x;
    int col = tid & 63;
    int node = tid >> 6;
    if (node >= N) return;
    float a;
    if (col < 32) {
        const float* r = num + (size_t)node * 5;
        float acc = bn[col];
        #pragma unroll
        for (int k = 0; k < 5; ++k) acc = fmaf(r[k], Wn[k * 32 + col], acc);
        a = acc;
    } else {
        int c = col & 31;
        a = fmaf(cat[node], Wc[c], bc[c]);
    }
    a = a > 0.f ? a : 0.01f * a;
    x0[(size_t)node * HID + 64 + col] = a;
}

// ---------------------------------------------------------------------------
// Dense [N,128]@[128,128] via LDS-free split-bf16 MFMA. Block 512 (8 waves);
// wave = 16 nodes x 128 cols (8 n_tiles). Optional fused epilogues:
//  BF16OUT: pack pairs via shfl, write bf16 rows (conv feed)
//  OUT2:    y=lrelu(.+b) then out[n,0:2] = y@W2 + b2 (final layer fusion)
// ---------------------------------------------------------------------------
template<bool BIAS, bool LRELU, bool DINV, bool BF16OUT, bool OUT2>
__global__ __launch_bounds__(512, 4) void gemm_mfma_kernel(
    const float* __restrict__ in, const short* __restrict__ WH, const short* __restrict__ WL,
    const float* __restrict__ b, const float* __restrict__ dinv,
    const float* __restrict__ W2, const float* __restrict__ b2,
    void* __restrict__ outp, int N)
{
    const int t = threadIdx.x;
    const int lane = t & 63;
    const int wv = t >> 6;
    const int n0 = blockIdx.x * 128;
    const int arow = n0 + wv * 16 + (lane & 15);
    const bool valid = arow < N;
    const float* __restrict__ ap = in + (size_t)arow * HID + ((lane >> 4) & 3) * 8;

    f32x4 acc[8] = {};

    #pragma unroll
    for (int kc = 0; kc < 4; ++kc) {
        float av[8] = {};
        if (valid) {
            float4 u0 = *reinterpret_cast<const float4*>(ap + kc * 32);
            float4 u1 = *reinterpret_cast<const float4*>(ap + kc * 32 + 4);
            av[0] = u0.x; av[1] = u0.y; av[2] = u0.z; av[3] = u0.w;
            av[4] = u1.x; av[5] = u1.y; av[6] = u1.z; av[7] = u1.w;
        }
        short8 ah, al;
        split8(av, ah, al);
        #pragma unroll
        for (int nt = 0; nt < 8; ++nt) {
            short8 wh = frag_ld(WH, kc * 8 + nt, lane);
            short8 wl = frag_ld(WL, kc * 8 + nt, lane);
            acc[nt] = __builtin_amdgcn_mfma_f32_16x16x32_bf16(ah, wh, acc[nt], 0, 0, 0);
            acc[nt] = __builtin_amdgcn_mfma_f32_16x16x32_bf16(ah, wl, acc[nt], 0, 0, 0);
            acc[nt] = __builtin_amdgcn_mfma_f32_16x16x32_bf16(al, wh, acc[nt], 0, 0, 0);
        }
    }

    const int cl = lane & 15;
    const int nodeb = n0 + wv * 16 + (lane >> 4) * 4;

    if (OUT2) {
        float p0[4] = {}, p1[4] = {};
        #pragma unroll
        for (int nt = 0; nt < 8; ++nt) {
            int c = nt * 16 + cl;
            float bb = BIAS ? b[c] : 0.f;
            float w20 = W2[c * 2 + 0], w21 = W2[c * 2 + 1];
            #pragma unroll
            for (int r = 0; r < 4; ++r) {
                float v = acc[nt][r] + bb;
                if (LRELU) v = v > 0.f ? v : 0.01f * v;
                p0[r] = fmaf(v, w20, p0[r]);
                p1[r] = fmaf(v, w21, p1[r]);
            }
        }
        #pragma unroll
        for (int r = 0; r < 4; ++r) {
            #pragma unroll
            for (int m = 1; m < 16; m <<= 1) {
                p0[r] += __shfl_xor(p0[r], m);
                p1[r] += __shfl_xor(p1[r], m);
            }
        }
        if (cl == 0) {
            float* out = reinterpret_cast<float*>(outp);
            #pragma unroll
            for (int r = 0; r < 4; ++r) {
                int node = nodeb + r;
                if (node < N) {
                    out[(size_t)node * 2 + 0] = p0[r] + b2[0];
                    out[(size_t)node * 2 + 1] = p1[r] + b2[1];
                }
            }
        }
        return;
    }

    float di[4];
    if (DINV) {
        #pragma unroll
        for (int r = 0; r < 4; ++r)
            di[r] = (nodeb + r < N) ? dinv[nodeb + r] : 0.f;
    }
    #pragma unroll
    for (int nt = 0; nt < 8; ++nt) {
        int c = nt * 16 + cl;
        float bb = BIAS ? b[c] : 0.f;
        #pragma unroll
        for (int r = 0; r < 4; ++r) {
            float v = acc[nt][r] + bb;
            if (LRELU) v = v > 0.f ? v : 0.01f * v;
            if (DINV)  v *= di[r];
            int node = nodeb + r;
            if (BF16OUT) {
                float pv = __shfl_xor(v, 1);
                if ((lane & 1) == 0 && node < N) {
                    unsigned u = pack_bf16(v, pv);
                    reinterpret_cast<unsigned*>(outp)[(size_t)node * (HID / 2) + (c >> 1)] = u;
                }
            } else {
                if (node < N)
                    reinterpret_cast<float*>(outp)[(size_t)node * HID + c] = v;
            }
        }
    }
}

// ---------------------------------------------------------------------------
// CSR build: histogram -> exclusive scan -> range-partitioned scatter
// ---------------------------------------------------------------------------
__global__ void hist_kernel(const int* __restrict__ dst, int* __restrict__ cnt, int E)
{
    int i = blockIdx.x * blockDim.x + threadIdx.x;
    int stride = gridDim.x * blockDim.x;
    for (; i < E; i += stride) atomicAdd(&cnt[dst[i]], 1);
}

__global__ void scan_block_kernel(const int* __restrict__ cnt, int* __restrict__ excl_out,
                                  int* __restrict__ part, int N)
{
    __shared__ int s[256];
    int t = threadIdx.x;
    int i = blockIdx.x * 256 + t;
    int v = (i < N) ? cnt[i] : 0;
    s[t] = v;
    __syncthreads();
    #pragma unroll
    for (int off = 1; off < 256; off <<= 1) {
        int x = (t >= off) ? s[t - off] : 0;
        __syncthreads();
        s[t] += x;
        __syncthreads();
    }
    int incl = s[t];
    if (i < N) excl_out[i] = incl - v;
    if (t == 255) part[blockIdx.x] = incl;
}

__global__ void scan_part_kernel(int* __restrict__ part, int B)
{
    __shared__ int s[512];
    int t = threadIdx.x;
    int v = (t < B) ? part[t] : 0;
    s[t] = v;
    __syncthreads();
    #pragma unroll
    for (int off = 1; off < 512; off <<= 1) {
        int x = (t >= off) ? s[t - off] : 0;
        __syncthreads();
        s[t] += x;
        __syncthreads();
    }
    int incl = s[t];
    if (t < B) part[t] = incl - v;
    if (t == B - 1) part[B] = incl;
}

__global__ void scan_final_kernel(int* __restrict__ row_ptr, const int* __restrict__ part,
                                  int* __restrict__ cursor, const int* __restrict__ cnt,
                                  float* __restrict__ dinv, int N, int B)
{
    int i = blockIdx.x * blockDim.x + threadIdx.x;
    if (i < N) {
        int rp = row_ptr[i] + part[i >> 8];
        row_ptr[i] = rp;
        cursor[i] = rp;
        dinv[i] = rsqrtf((float)(cnt[i] + 1));
    } else if (i == N) {
        row_ptr[N] = part[B];
    }
}

__global__ void scatter_kernel(const int* __restrict__ src, const int* __restrict__ dst,
                               int* __restrict__ cursor, int* __restrict__ col_idx,
                               int E, int lo, int hi)
{
    int i = blockIdx.x * blockDim.x + threadIdx.x;
    int stride = gridDim.x * blockDim.x;
    for (; i < E; i += stride) {
        int d = dst[i];
        if (d >= lo && d < hi) {
            int pos = atomicAdd(&cursor[d], 1);
            col_idx[pos] = src[i];
        }
    }
}

// ---------------------------------------------------------------------------
// GCN gather (bf16 hs): out[i] = dinv[i] * (hs[i] + sum hs[src]) + b
// ---------------------------------------------------------------------------
__global__ void conv_gather_bf16_kernel(const unsigned* __restrict__ hs,
                                        const int* __restrict__ row_ptr,
                                        const int* __restrict__ col_idx,
                                        const float* __restrict__ dinv,
                                        const float* __restrict__ b,
                                        float* __restrict__ out, int N)
{
    int tid = blockIdx.x * blockDim.x + threadIdx.x;
    int node = tid >> 5;
    int f4 = tid & 31;
    if (node >= N) return;
    const uint2* base = reinterpret_cast<const uint2*>(hs);
    float a0, a1, a2, a3;
    {
        uint2 v = base[(size_t)node * 32 + f4];
        a0 = bf16_lo(v.x); a1 = bf16_hi(v.x);
        a2 = bf16_lo(v.y); a3 = bf16_hi(v.y);
    }
    int e = row_ptr[node], end = row_ptr[node + 1];
    while (e < end) {
        int m = end - e;
        if (m >= 32) {
            int idx = col_idx[e + f4];
            #pragma unroll 8
            for (int j = 0; j < 32; ++j) {
                int s = __shfl(idx, j, 32);
                uint2 v = base[(size_t)s * 32 + f4];
                a0 += bf16_lo(v.x); a1 += bf16_hi(v.x);
                a2 += bf16_lo(v.y); a3 += bf16_hi(v.y);
            }
            e += 32;
        } else {
            int idx = (f4 < m) ? col_idx[e + f4] : 0;
            for (int j = 0; j < m; ++j) {
                int s = __shfl(idx, j, 32);
                uint2 v = base[(size_t)s * 32 + f4];
                a0 += bf16_lo(v.x); a1 += bf16_hi(v.x);
                a2 += bf16_lo(v.y); a3 += bf16_hi(v.y);
            }
            e = end;
        }
    }
    float di = dinv[node];
    float4 b4 = reinterpret_cast<const float4*>(b)[f4];
    float4 o;
    o.x = fmaf(di, a0, b4.x);
    o.y = fmaf(di, a1, b4.y);
    o.z = fmaf(di, a2, b4.z);
    o.w = fmaf(di, a3, b4.w);
    reinterpret_cast<float4*>(out)[(size_t)node * 32 + f4] = o;
}

extern "C" void kernel_launch(void* const* d_in, const int* in_sizes, int n_in,
                              void* d_out, int out_size, void* d_ws, size_t ws_size,
                              hipStream_t stream)
{
    const float* des   = (const float*)d_in[0];
    const float* tweet = (const float*)d_in[1];
    const float* num   = (const float*)d_in[2];
    const float* cat   = (const float*)d_in[3];
    const int*   eidx  = (const int*)d_in[4];
    const float* W_des = (const float*)d_in[5];  const float* b_des = (const float*)d_in[6];
    const float* W_tw  = (const float*)d_in[7];  const float* b_tw  = (const float*)d_in[8];
    const float* W_num = (const float*)d_in[9];  const float* b_num = (const float*)d_in[10];
    const float* W_cat = (const float*)d_in[11]; const float* b_cat = (const float*)d_in[12];
    const float* W_in  = (const float*)d_in[13]; const float* b_in  = (const float*)d_in[14];
    const float* W_g1  = (const float*)d_in[15]; const float* b_g1  = (const float*)d_in[16];
    const float* W_g2  = (const float*)d_in[17]; const float* b_g2  = (const float*)d_in[18];
    const float* W_o1  = (const float*)d_in[19]; const float* b_o1  = (const float*)d_in[20];
    const float* W_o2  = (const float*)d_in[21]; const float* b_o2  = (const float*)d_in[22];
    float* out = (float*)d_out;

    const int N = in_sizes[0] / 768;
    const int E = in_sizes[4] / 2;
    const int* src = eidx;
    const int* dst = eidx + E;

    // workspace layout
    char* ws = (char*)d_ws;
    const size_t szF = (size_t)N * HID * sizeof(float);
    float* F0 = (float*)ws;                    ws += szF;
    float* F1 = (float*)ws;                    ws += szF;
    float* F2 = (float*)ws;                    ws += szF;
    int* cnt      = (int*)ws;                  ws += ((size_t)N * 4 + 255) & ~255ULL;
    int* row_ptr  = (int*)ws;                  ws += (((size_t)N + 1) * 4 + 255) & ~255ULL;
    int* cursor   = (int*)ws;                  ws += ((size_t)N * 4 + 255) & ~255ULL;
    int* part     = (int*)ws;                  ws += 4096;
    float* dinv   = (float*)ws;                ws += ((size_t)N * 4 + 255) & ~255ULL;
    // fragment-ordered weights (bf16 hi/lo)
    const size_t sz768 = 768 * 32 * sizeof(short);    // 48 KB
    const size_t sz128 = 128 * 128 * sizeof(short);   // 32 KB
    short* wdes_hi = (short*)ws; ws += sz768;  short* wdes_lo = (short*)ws; ws += sz768;
    short* wtw_hi  = (short*)ws; ws += sz768;  short* wtw_lo  = (short*)ws; ws += sz768;
    short* win_hi  = (short*)ws; ws += sz128;  short* win_lo  = (short*)ws; ws += sz128;
    short* wg1_hi  = (short*)ws; ws += sz128;  short* wg1_lo  = (short*)ws; ws += sz128;
    short* wg2_hi  = (short*)ws; ws += sz128;  short* wg2_lo  = (short*)ws; ws += sz128;
    short* wo1_hi  = (short*)ws; ws += sz128;  short* wo1_lo  = (short*)ws; ws += sz128;
    int* col_idx  = (int*)ws;                  ws += (size_t)E * 4;

    const int B = (N + 255) / 256;  // scan blocks (<= 512)

    // ---- weight fragment conversion (one small kernel, 6 jobs) ----
    {
        dim3 grid(12, 6);
        convert_w_kernel<<<grid, 256, 0, stream>>>(
            W_des, W_tw, W_in, W_g1, W_g2, W_o1,
            wdes_hi, wdes_lo, wtw_hi, wtw_lo, win_hi, win_lo,
            wg1_hi, wg1_lo, wg2_hi, wg2_lo, wo1_hi, wo1_lo);
    }

    // ---- CSR build ----
    hipMemsetAsync(cnt, 0, (size_t)N * sizeof(int), stream);
    hist_kernel<<<1024, 256, 0, stream>>>(dst, cnt, E);
    scan_block_kernel<<<B, 256, 0, stream>>>(cnt, row_ptr, part, N);
    scan_part_kernel<<<1, 512, 0, stream>>>(part, B);
    scan_final_kernel<<<(N + 256) / 256 + 1, 256, 0, stream>>>(row_ptr, part, cursor, cnt, dinv, N, B);
    {
        const int NPART = 4;
        int step = (N + NPART - 1) / NPART;
        for (int p = 0; p < NPART; ++p) {
            int lo = p * step;
            int hi = (lo + step < N) ? lo + step : N;
            scatter_kernel<<<1024, 256, 0, stream>>>(src, dst, cursor, col_idx, E, lo, hi);
        }
    }

    // ---- encoder -> F0 ----
    {
        dim3 grid((N + 63) / 64, 2);
        enc_mfma2_kernel<<<grid, 256, 0, stream>>>(des, tweet, wdes_hi, wdes_lo,
                                                   wtw_hi, wtw_lo, b_des, b_tw, F0, N);
        enc_nc_kernel<<<((size_t)N * 64 + 255) / 256, 256, 0, stream>>>(num, cat, W_num, b_num, W_cat, b_cat, F0, N);
    }

    int ggrid = (N + 127) / 128;
    int cgrid = (int)(((size_t)N * 32 + 255) / 256);

    // ---- x1 = lrelu(x0 @ W_in + b_in) -> F1 (f32) ----
    gemm_mfma_kernel<true, true, false, false, false><<<ggrid, 512, 0, stream>>>(
        F0, win_hi, win_lo, b_in, nullptr, nullptr, nullptr, F1, N);

    // ---- conv1: hs1 = (x1 @ W_g1) * dinv -> F2 (bf16) ; c1 -> F0 (f32) ----
    gemm_mfma_kernel<false, false, true, true, false><<<ggrid, 512, 0, stream>>>(
        F1, wg1_hi, wg1_lo, nullptr, dinv, nullptr, nullptr, F2, N);
    conv_gather_bf16_kernel<<<cgrid, 256, 0, stream>>>((const unsigned*)F2, row_ptr, col_idx, dinv, b_g1, F0, N);

    // ---- conv2: hs2 = (c1 @ W_g2) * dinv -> F1 (bf16) ; c2 -> F2 (f32) ----
    gemm_mfma_kernel<false, false, true, true, false><<<ggrid, 512, 0, stream>>>(
        F0, wg2_hi, wg2_lo, nullptr, dinv, nullptr, nullptr, F1, N);
    conv_gather_bf16_kernel<<<cgrid, 256, 0, stream>>>((const unsigned*)F1, row_ptr, col_idx, dinv, b_g2, F2, N);

    // ---- out = lrelu(c2 @ W_o1 + b_o1) @ W_o2 + b_o2 (fused) ----
    gemm_mfma_kernel<true, true, false, false, true><<<ggrid, 512, 0, stream>>>(
        F2, wo1_hi, wo1_lo, b_o1, nullptr, W_o2, b_o2, out, N);
}

// Round 10
// 905.624 us; speedup vs baseline: 1.2351x; 1.0044x over previous
//
#include <hip/hip_runtime.h>
#include <hip/hip_bf16.h>
#include <cstdint>

#define HID 128

typedef short short8 __attribute__((ext_vector_type(8)));
typedef float f32x4 __attribute__((ext_vector_type(4)));

__device__ __forceinline__ unsigned pack_bf16(float a, float b)
{
    __hip_bfloat16 ha = __float2bfloat16(a);
    __hip_bfloat16 hb = __float2bfloat16(b);
    unsigned short ua = *reinterpret_cast<unsigned short*>(&ha);
    unsigned short ub = *reinterpret_cast<unsigned short*>(&hb);
    return (unsigned)ua | ((unsigned)ub << 16);
}

__device__ __forceinline__ float bf16_lo(unsigned u)
{
    unsigned v = u << 16;
    return *reinterpret_cast<float*>(&v);
}
__device__ __forceinline__ float bf16_hi(unsigned u)
{
    unsigned v = u & 0xffff0000u;
    return *reinterpret_cast<float*>(&v);
}

// truncate-split x = hi + lo (both bf16-representable), for 8 values
__device__ __forceinline__ void split8(const float* v, short8& h, short8& l)
{
    #pragma unroll
    for (int j = 0; j < 8; ++j) {
        unsigned bits = __float_as_uint(v[j]);
        h[j] = (short)(bits >> 16);
        unsigned hb = bits & 0xffff0000u;
        float lof = v[j] - __uint_as_float(hb);
        l[j] = (short)(__float_as_uint(lof) >> 16);
    }
}

// fragment array layout: frag row index = (kc*NT + nt)*64 + lane, 8 bf16 each.
// W frag (B-operand): col = nt*16 + (lane&15), k = kc*32 + ((lane>>4)&3)*8 + j.
__device__ __forceinline__ short8 frag_ld(const short* __restrict__ base, int tile, int lane)
{
    return *reinterpret_cast<const short8*>(base + (((size_t)tile * 64 + lane) << 3));
}

// ---------------------------------------------------------------------------
// One-shot weight conversion: f32 [K][C] -> fragment-ordered bf16 hi/lo.
// job 0/1: K=768,C=32 (W_des/W_tweet); jobs 2..5: K=128,C=128.
// ---------------------------------------------------------------------------
__global__ void convert_w_kernel(
    const float* W0, const float* W1, const float* W2,
    const float* W3, const float* W4, const float* W5,
    short* H0, short* L0, short* H1, short* L1, short* H2, short* L2,
    short* H3, short* L3, short* H4, short* L4, short* H5, short* L5)
{
    int job = blockIdx.y;
    const float* W; short* H; short* L; int K, C;
    switch (job) {
        case 0: W = W0; H = H0; L = L0; K = 768; C = 32;  break;
        case 1: W = W1; H = H1; L = L1; K = 768; C = 32;  break;
        case 2: W = W2; H = H2; L = L2; K = 128; C = 128; break;
        case 3: W = W3; H = H3; L = L3; K = 128; C = 128; break;
        case 4: W = W4; H = H4; L = L4; K = 128; C = 128; break;
        default: W = W5; H = H5; L = L5; K = 128; C = 128; break;
    }
    int NT = C >> 4;
    int rows = (K >> 5) * NT * 64;
    int r = blockIdx.x * blockDim.x + threadIdx.x;
    if (r >= rows) return;
    int lane = r & 63;
    int tile = r >> 6;              // kc*NT + nt
    int c = (tile % NT) * 16 + (lane & 15);
    int kbase = (tile / NT) * 32 + ((lane >> 4) & 3) * 8;
    float v[8];
    #pragma unroll
    for (int j = 0; j < 8; ++j) v[j] = W[(size_t)(kbase + j) * C + c];
    short8 h, l;
    split8(v, h, l);
    *reinterpret_cast<short8*>(H + ((size_t)r << 3)) = h;
    *reinterpret_cast<short8*>(L + ((size_t)r << 3)) = l;
}

// ---------------------------------------------------------------------------
// Encoder [N,768]@[768,32], LDS-free split-bf16 MFMA with explicit A-load
// software pipeline (prefetch kc+1 while MFMAing kc).
// ---------------------------------------------------------------------------
__global__ __launch_bounds__(256, 4) void enc_mfma2_kernel(
    const float* __restrict__ des, const float* __restrict__ tweet,
    const short* __restrict__ wdes_hi, const short* __restrict__ wdes_lo,
    const short* __restrict__ wtw_hi, const short* __restrict__ wtw_lo,
    const float* __restrict__ bd, const float* __restrict__ bt,
    float* __restrict__ x0, int N)
{
    const int mat = blockIdx.y;
    const float* __restrict__ X = mat ? tweet : des;
    const short* __restrict__ WH = mat ? wtw_hi : wdes_hi;
    const short* __restrict__ WL = mat ? wtw_lo : wdes_lo;
    const float* __restrict__ B = mat ? bt : bd;

    const int t = threadIdx.x;
    const int lane = t & 63;
    const int wv = t >> 6;
    const int n0 = blockIdx.x * 64;
    const int arow = n0 + wv * 16 + (lane & 15);
    const bool valid = arow < N;
    const float* __restrict__ ap = X + (size_t)arow * 768 + ((lane >> 4) & 3) * 8;

    f32x4 acc0 = {}, acc1 = {};

    float4 u0 = make_float4(0.f, 0.f, 0.f, 0.f);
    float4 u1 = make_float4(0.f, 0.f, 0.f, 0.f);
    if (valid) {
        u0 = *reinterpret_cast<const float4*>(ap);
        u1 = *reinterpret_cast<const float4*>(ap + 4);
    }

    for (int kc = 0; kc < 24; ++kc) {
        float av[8] = {u0.x, u0.y, u0.z, u0.w, u1.x, u1.y, u1.z, u1.w};
        // prefetch next chunk (hides HBM latency under split+MFMA below)
        if (kc < 23 && valid) {
            u0 = *reinterpret_cast<const float4*>(ap + (kc + 1) * 32);
            u1 = *reinterpret_cast<const float4*>(ap + (kc + 1) * 32 + 4);
        }
        short8 ah, al;
        split8(av, ah, al);
        short8 wh0 = frag_ld(WH, kc * 2 + 0, lane);
        short8 wl0 = frag_ld(WL, kc * 2 + 0, lane);
        short8 wh1 = frag_ld(WH, kc * 2 + 1, lane);
        short8 wl1 = frag_ld(WL, kc * 2 + 1, lane);
        acc0 = __builtin_amdgcn_mfma_f32_16x16x32_bf16(ah, wh0, acc0, 0, 0, 0);
        acc1 = __builtin_amdgcn_mfma_f32_16x16x32_bf16(ah, wh1, acc1, 0, 0, 0);
        acc0 = __builtin_amdgcn_mfma_f32_16x16x32_bf16(ah, wl0, acc0, 0, 0, 0);
        acc1 = __builtin_amdgcn_mfma_f32_16x16x32_bf16(ah, wl1, acc1, 0, 0, 0);
        acc0 = __builtin_amdgcn_mfma_f32_16x16x32_bf16(al, wh0, acc0, 0, 0, 0);
        acc1 = __builtin_amdgcn_mfma_f32_16x16x32_bf16(al, wh1, acc1, 0, 0, 0);
    }

    const int cl = lane & 15;
    float b0 = B[cl], b1 = B[16 + cl];
    const int nodeb = n0 + wv * 16 + (lane >> 4) * 4;
    #pragma unroll
    for (int r = 0; r < 4; ++r) {
        int node = nodeb + r;
        if (node < N) {
            float v0 = acc0[r] + b0; v0 = v0 > 0.f ? v0 : 0.01f * v0;
            float v1 = acc1[r] + b1; v1 = v1 > 0.f ? v1 : 0.01f * v1;
            x0[(size_t)node * HID + mat * 32 + cl] = v0;
            x0[(size_t)node * HID + mat * 32 + 16 + cl] = v1;
        }
    }
}

// x0[:,64:96] = lrelu(num @ W_num + b), x0[:,96:128] = lrelu(cat @ W_cat + b)
__global__ void enc_nc_kernel(const float* __restrict__ num, const float* __restrict__ cat,
                              const float* __restrict__ Wn, const float* __restrict__ bn,
                              const float* __restrict__ Wc, const float* __restrict__ bc,
                              float* __restrict__ x0, int N)
{
    int tid = blockIdx.x * blockDim.x + threadIdx.x;
    int col = tid & 63;
    int node = tid >> 6;
    if (node >= N) return;
    float a;
    if (col < 32) {
        const float* r = num + (size_t)node * 5;
        float acc = bn[col];
        #pragma unroll
        for (int k = 0; k < 5; ++k) acc = fmaf(r[k], Wn[k * 32 + col], acc);
        a = acc;
    } else {
        int c = col & 31;
        a = fmaf(cat[node], Wc[c], bc[c]);
    }
    a = a > 0.f ? a : 0.01f * a;
    x0[(size_t)node * HID + 64 + col] = a;
}

// ---------------------------------------------------------------------------
// Dense [N,128]@[128,128], LDS-free split-bf16 MFMA. Block 512 (8 waves);
// wave = 16 nodes x 128 cols (8 n_tiles).
//  BF16IN:  A is bf16 rows (exact frag load, 2-term MFMA)
//  BF16OUT: pack pairs via shfl, write bf16 rows (conv feed)
//  OUT2:    y=lrelu(.+b) then out[n,0:2] = y@W2 + b2 (final layer fusion)
// ---------------------------------------------------------------------------
template<bool BIAS, bool LRELU, bool DINV, bool BF16OUT, bool OUT2, bool BF16IN>
__global__ __launch_bounds__(512, 4) void gemm_mfma_kernel(
    const void* __restrict__ inp, const short* __restrict__ WH, const short* __restrict__ WL,
    const float* __restrict__ b, const float* __restrict__ dinv,
    const float* __restrict__ W2, const float* __restrict__ b2,
    void* __restrict__ outp, int N)
{
    const int t = threadIdx.x;
    const int lane = t & 63;
    const int wv = t >> 6;
    const int n0 = blockIdx.x * 128;
    const int arow = n0 + wv * 16 + (lane & 15);
    const bool valid = arow < N;

    f32x4 acc[8] = {};

    #pragma unroll
    for (int kc = 0; kc < 4; ++kc) {
        short8 ah = {}, al = {};
        if (BF16IN) {
            if (valid) {
                const short* apb = reinterpret_cast<const short*>(inp)
                                   + (size_t)arow * HID + ((lane >> 4) & 3) * 8;
                ah = *reinterpret_cast<const short8*>(apb + kc * 32);
            }
        } else {
            float av[8] = {};
            if (valid) {
                const float* ap = reinterpret_cast<const float*>(inp)
                                  + (size_t)arow * HID + ((lane >> 4) & 3) * 8;
                float4 u0 = *reinterpret_cast<const float4*>(ap + kc * 32);
                float4 u1 = *reinterpret_cast<const float4*>(ap + kc * 32 + 4);
                av[0] = u0.x; av[1] = u0.y; av[2] = u0.z; av[3] = u0.w;
                av[4] = u1.x; av[5] = u1.y; av[6] = u1.z; av[7] = u1.w;
            }
            split8(av, ah, al);
        }
        #pragma unroll
        for (int nt = 0; nt < 8; ++nt) {
            short8 wh = frag_ld(WH, kc * 8 + nt, lane);
            short8 wl = frag_ld(WL, kc * 8 + nt, lane);
            acc[nt] = __builtin_amdgcn_mfma_f32_16x16x32_bf16(ah, wh, acc[nt], 0, 0, 0);
            acc[nt] = __builtin_amdgcn_mfma_f32_16x16x32_bf16(ah, wl, acc[nt], 0, 0, 0);
            if (!BF16IN)
                acc[nt] = __builtin_amdgcn_mfma_f32_16x16x32_bf16(al, wh, acc[nt], 0, 0, 0);
        }
    }

    const int cl = lane & 15;
    const int nodeb = n0 + wv * 16 + (lane >> 4) * 4;

    if (OUT2) {
        float p0[4] = {}, p1[4] = {};
        #pragma unroll
        for (int nt = 0; nt < 8; ++nt) {
            int c = nt * 16 + cl;
            float bb = BIAS ? b[c] : 0.f;
            float w20 = W2[c * 2 + 0], w21 = W2[c * 2 + 1];
            #pragma unroll
            for (int r = 0; r < 4; ++r) {
                float v = acc[nt][r] + bb;
                if (LRELU) v = v > 0.f ? v : 0.01f * v;
                p0[r] = fmaf(v, w20, p0[r]);
                p1[r] = fmaf(v, w21, p1[r]);
            }
        }
        #pragma unroll
        for (int r = 0; r < 4; ++r) {
            #pragma unroll
            for (int m = 1; m < 16; m <<= 1) {
                p0[r] += __shfl_xor(p0[r], m);
                p1[r] += __shfl_xor(p1[r], m);
            }
        }
        if (cl == 0) {
            float* out = reinterpret_cast<float*>(outp);
            #pragma unroll
            for (int r = 0; r < 4; ++r) {
                int node = nodeb + r;
                if (node < N) {
                    out[(size_t)node * 2 + 0] = p0[r] + b2[0];
                    out[(size_t)node * 2 + 1] = p1[r] + b2[1];
                }
            }
        }
        return;
    }

    float di[4];
    if (DINV) {
        #pragma unroll
        for (int r = 0; r < 4; ++r)
            di[r] = (nodeb + r < N) ? dinv[nodeb + r] : 0.f;
    }
    #pragma unroll
    for (int nt = 0; nt < 8; ++nt) {
        int c = nt * 16 + cl;
        float bb = BIAS ? b[c] : 0.f;
        #pragma unroll
        for (int r = 0; r < 4; ++r) {
            float v = acc[nt][r] + bb;
            if (LRELU) v = v > 0.f ? v : 0.01f * v;
            if (DINV)  v *= di[r];
            int node = nodeb + r;
            if (BF16OUT) {
                float pv = __shfl_xor(v, 1);
                if ((lane & 1) == 0 && node < N) {
                    unsigned u = pack_bf16(v, pv);
                    reinterpret_cast<unsigned*>(outp)[(size_t)node * (HID / 2) + (c >> 1)] = u;
                }
            } else {
                if (node < N)
                    reinterpret_cast<float*>(outp)[(size_t)node * HID + c] = v;
            }
        }
    }
}

// ---------------------------------------------------------------------------
// CSR build: histogram -> exclusive scan -> range-partitioned scatter
// ---------------------------------------------------------------------------
__global__ void hist_kernel(const int* __restrict__ dst, int* __restrict__ cnt, int E)
{
    int i = blockIdx.x * blockDim.x + threadIdx.x;
    int stride = gridDim.x * blockDim.x;
    for (; i < E; i += stride) atomicAdd(&cnt[dst[i]], 1);
}

__global__ void scan_block_kernel(const int* __restrict__ cnt, int* __restrict__ excl_out,
                                  int* __restrict__ part, int N)
{
    __shared__ int s[256];
    int t = threadIdx.x;
    int i = blockIdx.x * 256 + t;
    int v = (i < N) ? cnt[i] : 0;
    s[t] = v;
    __syncthreads();
    #pragma unroll
    for (int off = 1; off < 256; off <<= 1) {
        int x = (t >= off) ? s[t - off] : 0;
        __syncthreads();
        s[t] += x;
        __syncthreads();
    }
    int incl = s[t];
    if (i < N) excl_out[i] = incl - v;
    if (t == 255) part[blockIdx.x] = incl;
}

__global__ void scan_part_kernel(int* __restrict__ part, int B)
{
    __shared__ int s[512];
    int t = threadIdx.x;
    int v = (t < B) ? part[t] : 0;
    s[t] = v;
    __syncthreads();
    #pragma unroll
    for (int off = 1; off < 512; off <<= 1) {
        int x = (t >= off) ? s[t - off] : 0;
        __syncthreads();
        s[t] += x;
        __syncthreads();
    }
    int incl = s[t];
    if (t < B) part[t] = incl - v;
    if (t == B - 1) part[B] = incl;
}

__global__ void scan_final_kernel(int* __restrict__ row_ptr, const int* __restrict__ part,
                                  int* __restrict__ cursor, const int* __restrict__ cnt,
                                  float* __restrict__ dinv, int N, int B)
{
    int i = blockIdx.x * blockDim.x + threadIdx.x;
    if (i < N) {
        int rp = row_ptr[i] + part[i >> 8];
        row_ptr[i] = rp;
        cursor[i] = rp;
        dinv[i] = rsqrtf((float)(cnt[i] + 1));
    } else if (i == N) {
        row_ptr[N] = part[B];
    }
}

__global__ void scatter_kernel(const int* __restrict__ src, const int* __restrict__ dst,
                               int* __restrict__ cursor, int* __restrict__ col_idx,
                               int E, int lo, int hi)
{
    int i = blockIdx.x * blockDim.x + threadIdx.x;
    int stride = gridDim.x * blockDim.x;
    for (; i < E; i += stride) {
        int d = dst[i];
        if (d >= lo && d < hi) {
            int pos = atomicAdd(&cursor[d], 1);
            col_idx[pos] = src[i];
        }
    }
}

// ---------------------------------------------------------------------------
// GCN gather (bf16 hs in, bf16 out): out[i] = dinv[i]*(hs[i]+sum hs[src]) + b
// 32 lanes per node, 4 bf16 (8B) per lane. Accumulate f32, write bf16.
// ---------------------------------------------------------------------------
__global__ void conv_gather_bf16_kernel(const unsigned* __restrict__ hs,
                                        const int* __restrict__ row_ptr,
                                        const int* __restrict__ col_idx,
                                        const float* __restrict__ dinv,
                                        const float* __restrict__ b,
                                        unsigned* __restrict__ outp, int N)
{
    int tid = blockIdx.x * blockDim.x + threadIdx.x;
    int node = tid >> 5;
    int f4 = tid & 31;
    if (node >= N) return;
    const uint2* base = reinterpret_cast<const uint2*>(hs);
    float a0, a1, a2, a3;
    {
        uint2 v = base[(size_t)node * 32 + f4];
        a0 = bf16_lo(v.x); a1 = bf16_hi(v.x);
        a2 = bf16_lo(v.y); a3 = bf16_hi(v.y);
    }
    int e = row_ptr[node], end = row_ptr[node + 1];
    while (e < end) {
        int m = end - e;
        if (m >= 32) {
            int idx = col_idx[e + f4];
            #pragma unroll 8
            for (int j = 0; j < 32; ++j) {
                int s = __shfl(idx, j, 32);
                uint2 v = base[(size_t)s * 32 + f4];
                a0 += bf16_lo(v.x); a1 += bf16_hi(v.x);
                a2 += bf16_lo(v.y); a3 += bf16_hi(v.y);
            }
            e += 32;
        } else {
            int idx = (f4 < m) ? col_idx[e + f4] : 0;
            for (int j = 0; j < m; ++j) {
                int s = __shfl(idx, j, 32);
                uint2 v = base[(size_t)s * 32 + f4];
                a0 += bf16_lo(v.x); a1 += bf16_hi(v.x);
                a2 += bf16_lo(v.y); a3 += bf16_hi(v.y);
            }
            e = end;
        }
    }
    float di = dinv[node];
    float4 b4 = reinterpret_cast<const float4*>(b)[f4];
    unsigned o0 = pack_bf16(fmaf(di, a0, b4.x), fmaf(di, a1, b4.y));
    unsigned o1 = pack_bf16(fmaf(di, a2, b4.z), fmaf(di, a3, b4.w));
    reinterpret_cast<uint2*>(outp)[(size_t)node * 32 + f4] = make_uint2(o0, o1);
}

extern "C" void kernel_launch(void* const* d_in, const int* in_sizes, int n_in,
                              void* d_out, int out_size, void* d_ws, size_t ws_size,
                              hipStream_t stream)
{
    const float* des   = (const float*)d_in[0];
    const float* tweet = (const float*)d_in[1];
    const float* num   = (const float*)d_in[2];
    const float* cat   = (const float*)d_in[3];
    const int*   eidx  = (const int*)d_in[4];
    const float* W_des = (const float*)d_in[5];  const float* b_des = (const float*)d_in[6];
    const float* W_tw  = (const float*)d_in[7];  const float* b_tw  = (const float*)d_in[8];
    const float* W_num = (const float*)d_in[9];  const float* b_num = (const float*)d_in[10];
    const float* W_cat = (const float*)d_in[11]; const float* b_cat = (const float*)d_in[12];
    const float* W_in  = (const float*)d_in[13]; const float* b_in  = (const float*)d_in[14];
    const float* W_g1  = (const float*)d_in[15]; const float* b_g1  = (const float*)d_in[16];
    const float* W_g2  = (const float*)d_in[17]; const float* b_g2  = (const float*)d_in[18];
    const float* W_o1  = (const float*)d_in[19]; const float* b_o1  = (const float*)d_in[20];
    const float* W_o2  = (const float*)d_in[21]; const float* b_o2  = (const float*)d_in[22];
    float* out = (float*)d_out;

    const int N = in_sizes[0] / 768;
    const int E = in_sizes[4] / 2;
    const int* src = eidx;
    const int* dst = eidx + E;

    // workspace layout
    char* ws = (char*)d_ws;
    const size_t szF = (size_t)N * HID * sizeof(float);
    float* F0 = (float*)ws;                    ws += szF;
    float* F1 = (float*)ws;                    ws += szF;
    float* F2 = (float*)ws;                    ws += szF;
    int* cnt      = (int*)ws;                  ws += ((size_t)N * 4 + 255) & ~255ULL;
    int* row_ptr  = (int*)ws;                  ws += (((size_t)N + 1) * 4 + 255) & ~255ULL;
    int* cursor   = (int*)ws;                  ws += ((size_t)N * 4 + 255) & ~255ULL;
    int* part     = (int*)ws;                  ws += 4096;
    float* dinv   = (float*)ws;                ws += ((size_t)N * 4 + 255) & ~255ULL;
    // fragment-ordered weights (bf16 hi/lo)
    const size_t sz768 = 768 * 32 * sizeof(short);    // 48 KB
    const size_t sz128 = 128 * 128 * sizeof(short);   // 32 KB
    short* wdes_hi = (short*)ws; ws += sz768;  short* wdes_lo = (short*)ws; ws += sz768;
    short* wtw_hi  = (short*)ws; ws += sz768;  short* wtw_lo  = (short*)ws; ws += sz768;
    short* win_hi  = (short*)ws; ws += sz128;  short* win_lo  = (short*)ws; ws += sz128;
    short* wg1_hi  = (short*)ws; ws += sz128;  short* wg1_lo  = (short*)ws; ws += sz128;
    short* wg2_hi  = (short*)ws; ws += sz128;  short* wg2_lo  = (short*)ws; ws += sz128;
    short* wo1_hi  = (short*)ws; ws += sz128;  short* wo1_lo  = (short*)ws; ws += sz128;
    int* col_idx  = (int*)ws;                  ws += (size_t)E * 4;

    const int B = (N + 255) / 256;  // scan blocks (<= 512)

    // ---- weight fragment conversion (one small kernel, 6 jobs) ----
    {
        dim3 grid(12, 6);
        convert_w_kernel<<<grid, 256, 0, stream>>>(
            W_des, W_tw, W_in, W_g1, W_g2, W_o1,
            wdes_hi, wdes_lo, wtw_hi, wtw_lo, win_hi, win_lo,
            wg1_hi, wg1_lo, wg2_hi, wg2_lo, wo1_hi, wo1_lo);
    }

    // ---- CSR build ----
    hipMemsetAsync(cnt, 0, (size_t)N * sizeof(int), stream);
    hist_kernel<<<1024, 256, 0, stream>>>(dst, cnt, E);
    scan_block_kernel<<<B, 256, 0, stream>>>(cnt, row_ptr, part, N);
    scan_part_kernel<<<1, 512, 0, stream>>>(part, B);
    scan_final_kernel<<<(N + 256) / 256 + 1, 256, 0, stream>>>(row_ptr, part, cursor, cnt, dinv, N, B);
    {
        const int NPART = 4;
        int step = (N + NPART - 1) / NPART;
        for (int p = 0; p < NPART; ++p) {
            int lo = p * step;
            int hi = (lo + step < N) ? lo + step : N;
            scatter_kernel<<<1024, 256, 0, stream>>>(src, dst, cursor, col_idx, E, lo, hi);
        }
    }

    // ---- encoder -> F0 ----
    {
        dim3 grid((N + 63) / 64, 2);
        enc_mfma2_kernel<<<grid, 256, 0, stream>>>(des, tweet, wdes_hi, wdes_lo,
                                                   wtw_hi, wtw_lo, b_des, b_tw, F0, N);
        enc_nc_kernel<<<((size_t)N * 64 + 255) / 256, 256, 0, stream>>>(num, cat, W_num, b_num, W_cat, b_cat, F0, N);
    }

    int ggrid = (N + 127) / 128;
    int cgrid = (int)(((size_t)N * 32 + 255) / 256);

    // ---- x1 = lrelu(x0 @ W_in + b_in) -> F1 (f32) ----
    gemm_mfma_kernel<true, true, false, false, false, false><<<ggrid, 512, 0, stream>>>(
        F0, win_hi, win_lo, b_in, nullptr, nullptr, nullptr, F1, N);

    // ---- conv1: hs1 = (x1 @ W_g1)*dinv -> F2 (bf16); c1 = gather -> F0 (bf16) ----
    gemm_mfma_kernel<false, false, true, true, false, false><<<ggrid, 512, 0, stream>>>(
        F1, wg1_hi, wg1_lo, nullptr, dinv, nullptr, nullptr, F2, N);
    conv_gather_bf16_kernel<<<cgrid, 256, 0, stream>>>((const unsigned*)F2, row_ptr, col_idx, dinv, b_g1, (unsigned*)F0, N);

    // ---- conv2: hs2 = (c1 @ W_g2)*dinv -> F1 (bf16); c2 = gather -> F2 (bf16) ----
    gemm_mfma_kernel<false, false, true, true, false, true><<<ggrid, 512, 0, stream>>>(
        F0, wg2_hi, wg2_lo, nullptr, dinv, nullptr, nullptr, F1, N);
    conv_gather_bf16_kernel<<<cgrid, 256, 0, stream>>>((const unsigned*)F1, row_ptr, col_idx, dinv, b_g2, (unsigned*)F2, N);

    // ---- out = lrelu(c2 @ W_o1 + b_o1) @ W_o2 + b_o2 (fused, bf16 in) ----
    gemm_mfma_kernel<true, true, false, false, true, true><<<ggrid, 512, 0, stream>>>(
        F2, wo1_hi, wo1_lo, b_o1, nullptr, W_o2, b_o2, out, N);
}

// Round 11
// 879.648 us; speedup vs baseline: 1.2716x; 1.0295x over previous
//
#include <hip/hip_runtime.h>
#include <hip/hip_bf16.h>
#include <cstdint>

#define HID 128

typedef short short8 __attribute__((ext_vector_type(8)));
typedef float f32x4 __attribute__((ext_vector_type(4)));

__device__ __forceinline__ unsigned pack_bf16(float a, float b)
{
    __hip_bfloat16 ha = __float2bfloat16(a);
    __hip_bfloat16 hb = __float2bfloat16(b);
    unsigned short ua = *reinterpret_cast<unsigned short*>(&ha);
    unsigned short ub = *reinterpret_cast<unsigned short*>(&hb);
    return (unsigned)ua | ((unsigned)ub << 16);
}

__device__ __forceinline__ float bf16_lo(unsigned u)
{
    unsigned v = u << 16;
    return *reinterpret_cast<float*>(&v);
}
__device__ __forceinline__ float bf16_hi(unsigned u)
{
    unsigned v = u & 0xffff0000u;
    return *reinterpret_cast<float*>(&v);
}

// truncate-split x = hi + lo (both bf16-representable), for 8 values
__device__ __forceinline__ void split8(const float* v, short8& h, short8& l)
{
    #pragma unroll
    for (int j = 0; j < 8; ++j) {
        unsigned bits = __float_as_uint(v[j]);
        h[j] = (short)(bits >> 16);
        unsigned hb = bits & 0xffff0000u;
        float lof = v[j] - __uint_as_float(hb);
        l[j] = (short)(__float_as_uint(lof) >> 16);
    }
}

// fragment array layout: frag row index = (kc*NT + nt)*64 + lane, 8 bf16 each.
__device__ __forceinline__ short8 frag_ld(const short* __restrict__ base, int tile, int lane)
{
    return *reinterpret_cast<const short8*>(base + (((size_t)tile * 64 + lane) << 3));
}

// ---------------------------------------------------------------------------
// One-shot weight conversion: f32 [K][C] -> fragment-ordered bf16 hi/lo.
// ---------------------------------------------------------------------------
__global__ void convert_w_kernel(
    const float* W0, const float* W1, const float* W2,
    const float* W3, const float* W4, const float* W5,
    short* H0, short* L0, short* H1, short* L1, short* H2, short* L2,
    short* H3, short* L3, short* H4, short* L4, short* H5, short* L5)
{
    int job = blockIdx.y;
    const float* W; short* H; short* L; int K, C;
    switch (job) {
        case 0: W = W0; H = H0; L = L0; K = 768; C = 32;  break;
        case 1: W = W1; H = H1; L = L1; K = 768; C = 32;  break;
        case 2: W = W2; H = H2; L = L2; K = 128; C = 128; break;
        case 3: W = W3; H = H3; L = L3; K = 128; C = 128; break;
        case 4: W = W4; H = H4; L = L4; K = 128; C = 128; break;
        default: W = W5; H = H5; L = L5; K = 128; C = 128; break;
    }
    int NT = C >> 4;
    int rows = (K >> 5) * NT * 64;
    int r = blockIdx.x * blockDim.x + threadIdx.x;
    if (r >= rows) return;
    int lane = r & 63;
    int tile = r >> 6;
    int c = (tile % NT) * 16 + (lane & 15);
    int kbase = (tile / NT) * 32 + ((lane >> 4) & 3) * 8;
    float v[8];
    #pragma unroll
    for (int j = 0; j < 8; ++j) v[j] = W[(size_t)(kbase + j) * C + c];
    short8 h, l;
    split8(v, h, l);
    *reinterpret_cast<short8*>(H + ((size_t)r << 3)) = h;
    *reinterpret_cast<short8*>(L + ((size_t)r << 3)) = l;
}

// ---------------------------------------------------------------------------
// Encoder [N,768]@[768,32], LDS-free split-bf16 MFMA, prefetch depth 2
// (4 dwordx4 in flight per lane).
// ---------------------------------------------------------------------------
__global__ __launch_bounds__(256, 4) void enc_mfma2_kernel(
    const float* __restrict__ des, const float* __restrict__ tweet,
    const short* __restrict__ wdes_hi, const short* __restrict__ wdes_lo,
    const short* __restrict__ wtw_hi, const short* __restrict__ wtw_lo,
    const float* __restrict__ bd, const float* __restrict__ bt,
    float* __restrict__ x0, int N)
{
    const int mat = blockIdx.y;
    const float* __restrict__ X = mat ? tweet : des;
    const short* __restrict__ WH = mat ? wtw_hi : wdes_hi;
    const short* __restrict__ WL = mat ? wtw_lo : wdes_lo;
    const float* __restrict__ B = mat ? bt : bd;

    const int t = threadIdx.x;
    const int lane = t & 63;
    const int wv = t >> 6;
    const int n0 = blockIdx.x * 64;
    const int arow = n0 + wv * 16 + (lane & 15);
    const bool valid = arow < N;
    const float* __restrict__ ap = X + (size_t)arow * 768 + ((lane >> 4) & 3) * 8;

    f32x4 acc0 = {}, acc1 = {};

    float4 p0[2], p1[2];   // 2-deep prefetch ring
    #pragma unroll
    for (int d = 0; d < 2; ++d) {
        p0[d] = make_float4(0.f, 0.f, 0.f, 0.f);
        p1[d] = make_float4(0.f, 0.f, 0.f, 0.f);
        if (valid) {
            p0[d] = *reinterpret_cast<const float4*>(ap + d * 32);
            p1[d] = *reinterpret_cast<const float4*>(ap + d * 32 + 4);
        }
    }

    for (int kc = 0; kc < 24; ++kc) {
        int slot = kc & 1;
        float4 u0 = p0[slot], u1 = p1[slot];
        // refill this slot with kc+2 (stays 2 deep in flight)
        if (kc < 22 && valid) {
            p0[slot] = *reinterpret_cast<const float4*>(ap + (kc + 2) * 32);
            p1[slot] = *reinterpret_cast<const float4*>(ap + (kc + 2) * 32 + 4);
        }
        float av[8] = {u0.x, u0.y, u0.z, u0.w, u1.x, u1.y, u1.z, u1.w};
        short8 ah, al;
        split8(av, ah, al);
        short8 wh0 = frag_ld(WH, kc * 2 + 0, lane);
        short8 wl0 = frag_ld(WL, kc * 2 + 0, lane);
        short8 wh1 = frag_ld(WH, kc * 2 + 1, lane);
        short8 wl1 = frag_ld(WL, kc * 2 + 1, lane);
        acc0 = __builtin_amdgcn_mfma_f32_16x16x32_bf16(ah, wh0, acc0, 0, 0, 0);
        acc1 = __builtin_amdgcn_mfma_f32_16x16x32_bf16(ah, wh1, acc1, 0, 0, 0);
        acc0 = __builtin_amdgcn_mfma_f32_16x16x32_bf16(ah, wl0, acc0, 0, 0, 0);
        acc1 = __builtin_amdgcn_mfma_f32_16x16x32_bf16(ah, wl1, acc1, 0, 0, 0);
        acc0 = __builtin_amdgcn_mfma_f32_16x16x32_bf16(al, wh0, acc0, 0, 0, 0);
        acc1 = __builtin_amdgcn_mfma_f32_16x16x32_bf16(al, wh1, acc1, 0, 0, 0);
    }

    const int cl = lane & 15;
    float b0 = B[cl], b1 = B[16 + cl];
    const int nodeb = n0 + wv * 16 + (lane >> 4) * 4;
    #pragma unroll
    for (int r = 0; r < 4; ++r) {
        int node = nodeb + r;
        if (node < N) {
            float v0 = acc0[r] + b0; v0 = v0 > 0.f ? v0 : 0.01f * v0;
            float v1 = acc1[r] + b1; v1 = v1 > 0.f ? v1 : 0.01f * v1;
            x0[(size_t)node * HID + mat * 32 + cl] = v0;
            x0[(size_t)node * HID + mat * 32 + 16 + cl] = v1;
        }
    }
}

// x0[:,64:96] = lrelu(num @ W_num + b), x0[:,96:128] = lrelu(cat @ W_cat + b)
__global__ void enc_nc_kernel(const float* __restrict__ num, const float* __restrict__ cat,
                              const float* __restrict__ Wn, const float* __restrict__ bn,
                              const float* __restrict__ Wc, const float* __restrict__ bc,
                              float* __restrict__ x0, int N)
{
    int tid = blockIdx.x * blockDim.x + threadIdx.x;
    int col = tid & 63;
    int node = tid >> 6;
    if (node >= N) return;
    float a;
    if (col < 32) {
        const float* r = num + (size_t)node * 5;
        float acc = bn[col];
        #pragma unroll
        for (int k = 0; k < 5; ++k) acc = fmaf(r[k], Wn[k * 32 + col], acc);
        a = acc;
    } else {
        int c = col & 31;
        a = fmaf(cat[node], Wc[c], bc[c]);
    }
    a = a > 0.f ? a : 0.01f * a;
    x0[(size_t)node * HID + 64 + col] = a;
}

// ---------------------------------------------------------------------------
// Dense [N,128]@[128,128], LDS-free split-bf16 MFMA. (R10 structure)
// ---------------------------------------------------------------------------
template<bool BIAS, bool LRELU, bool DINV, bool BF16OUT, bool OUT2, bool BF16IN>
__global__ __launch_bounds__(512, 4) void gemm_mfma_kernel(
    const void* __restrict__ inp, const short* __restrict__ WH, const short* __restrict__ WL,
    const float* __restrict__ b, const float* __restrict__ dinv,
    const float* __restrict__ W2, const float* __restrict__ b2,
    void* __restrict__ outp, int N)
{
    const int t = threadIdx.x;
    const int lane = t & 63;
    const int wv = t >> 6;
    const int n0 = blockIdx.x * 128;
    const int arow = n0 + wv * 16 + (lane & 15);
    const bool valid = arow < N;

    f32x4 acc[8] = {};

    #pragma unroll
    for (int kc = 0; kc < 4; ++kc) {
        short8 ah = {}, al = {};
        if (BF16IN) {
            if (valid) {
                const short* apb = reinterpret_cast<const short*>(inp)
                                   + (size_t)arow * HID + ((lane >> 4) & 3) * 8;
                ah = *reinterpret_cast<const short8*>(apb + kc * 32);
            }
        } else {
            float av[8] = {};
            if (valid) {
                const float* ap = reinterpret_cast<const float*>(inp)
                                  + (size_t)arow * HID + ((lane >> 4) & 3) * 8;
                float4 u0 = *reinterpret_cast<const float4*>(ap + kc * 32);
                float4 u1 = *reinterpret_cast<const float4*>(ap + kc * 32 + 4);
                av[0] = u0.x; av[1] = u0.y; av[2] = u0.z; av[3] = u0.w;
                av[4] = u1.x; av[5] = u1.y; av[6] = u1.z; av[7] = u1.w;
            }
            split8(av, ah, al);
        }
        #pragma unroll
        for (int nt = 0; nt < 8; ++nt) {
            short8 wh = frag_ld(WH, kc * 8 + nt, lane);
            short8 wl = frag_ld(WL, kc * 8 + nt, lane);
            acc[nt] = __builtin_amdgcn_mfma_f32_16x16x32_bf16(ah, wh, acc[nt], 0, 0, 0);
            acc[nt] = __builtin_amdgcn_mfma_f32_16x16x32_bf16(ah, wl, acc[nt], 0, 0, 0);
            if (!BF16IN)
                acc[nt] = __builtin_amdgcn_mfma_f32_16x16x32_bf16(al, wh, acc[nt], 0, 0, 0);
        }
    }

    const int cl = lane & 15;
    const int nodeb = n0 + wv * 16 + (lane >> 4) * 4;

    if (OUT2) {
        float p0[4] = {}, p1[4] = {};
        #pragma unroll
        for (int nt = 0; nt < 8; ++nt) {
            int c = nt * 16 + cl;
            float bb = BIAS ? b[c] : 0.f;
            float w20 = W2[c * 2 + 0], w21 = W2[c * 2 + 1];
            #pragma unroll
            for (int r = 0; r < 4; ++r) {
                float v = acc[nt][r] + bb;
                if (LRELU) v = v > 0.f ? v : 0.01f * v;
                p0[r] = fmaf(v, w20, p0[r]);
                p1[r] = fmaf(v, w21, p1[r]);
            }
        }
        #pragma unroll
        for (int r = 0; r < 4; ++r) {
            #pragma unroll
            for (int m = 1; m < 16; m <<= 1) {
                p0[r] += __shfl_xor(p0[r], m);
                p1[r] += __shfl_xor(p1[r], m);
            }
        }
        if (cl == 0) {
            float* out = reinterpret_cast<float*>(outp);
            #pragma unroll
            for (int r = 0; r < 4; ++r) {
                int node = nodeb + r;
                if (node < N) {
                    out[(size_t)node * 2 + 0] = p0[r] + b2[0];
                    out[(size_t)node * 2 + 1] = p1[r] + b2[1];
                }
            }
        }
        return;
    }

    float di[4];
    if (DINV) {
        #pragma unroll
        for (int r = 0; r < 4; ++r)
            di[r] = (nodeb + r < N) ? dinv[nodeb + r] : 0.f;
    }
    #pragma unroll
    for (int nt = 0; nt < 8; ++nt) {
        int c = nt * 16 + cl;
        float bb = BIAS ? b[c] : 0.f;
        #pragma unroll
        for (int r = 0; r < 4; ++r) {
            float v = acc[nt][r] + bb;
            if (LRELU) v = v > 0.f ? v : 0.01f * v;
            if (DINV)  v *= di[r];
            int node = nodeb + r;
            if (BF16OUT) {
                float pv = __shfl_xor(v, 1);
                if ((lane & 1) == 0 && node < N) {
                    unsigned u = pack_bf16(v, pv);
                    reinterpret_cast<unsigned*>(outp)[(size_t)node * (HID / 2) + (c >> 1)] = u;
                }
            } else {
                if (node < N)
                    reinterpret_cast<float*>(outp)[(size_t)node * HID + c] = v;
            }
        }
    }
}

// ---------------------------------------------------------------------------
// CSR build: histogram -> exclusive scan -> range-partitioned scatter
// ---------------------------------------------------------------------------
__global__ void hist_kernel(const int* __restrict__ dst, int* __restrict__ cnt, int E)
{
    int i = blockIdx.x * blockDim.x + threadIdx.x;
    int stride = gridDim.x * blockDim.x;
    for (; i < E; i += stride) atomicAdd(&cnt[dst[i]], 1);
}

__global__ void scan_block_kernel(const int* __restrict__ cnt, int* __restrict__ excl_out,
                                  int* __restrict__ part, int N)
{
    __shared__ int s[256];
    int t = threadIdx.x;
    int i = blockIdx.x * 256 + t;
    int v = (i < N) ? cnt[i] : 0;
    s[t] = v;
    __syncthreads();
    #pragma unroll
    for (int off = 1; off < 256; off <<= 1) {
        int x = (t >= off) ? s[t - off] : 0;
        __syncthreads();
        s[t] += x;
        __syncthreads();
    }
    int incl = s[t];
    if (i < N) excl_out[i] = incl - v;
    if (t == 255) part[blockIdx.x] = incl;
}

__global__ void scan_part_kernel(int* __restrict__ part, int B)
{
    __shared__ int s[512];
    int t = threadIdx.x;
    int v = (t < B) ? part[t] : 0;
    s[t] = v;
    __syncthreads();
    #pragma unroll
    for (int off = 1; off < 512; off <<= 1) {
        int x = (t >= off) ? s[t - off] : 0;
        __syncthreads();
        s[t] += x;
        __syncthreads();
    }
    int incl = s[t];
    if (t < B) part[t] = incl - v;
    if (t == B - 1) part[B] = incl;
}

__global__ void scan_final_kernel(int* __restrict__ row_ptr, const int* __restrict__ part,
                                  int* __restrict__ cursor, const int* __restrict__ cnt,
                                  float* __restrict__ dinv, int N, int B)
{
    int i = blockIdx.x * blockDim.x + threadIdx.x;
    if (i < N) {
        int rp = row_ptr[i] + part[i >> 8];
        row_ptr[i] = rp;
        cursor[i] = rp;
        dinv[i] = rsqrtf((float)(cnt[i] + 1));
    } else if (i == N) {
        row_ptr[N] = part[B];
    }
}

__global__ void scatter_kernel(const int* __restrict__ src, const int* __restrict__ dst,
                               int* __restrict__ cursor, int* __restrict__ col_idx,
                               int E, int lo, int hi)
{
    int i = blockIdx.x * blockDim.x + threadIdx.x;
    int stride = gridDim.x * blockDim.x;
    for (; i < E; i += stride) {
        int d = dst[i];
        if (d >= lo && d < hi) {
            int pos = atomicAdd(&cursor[d], 1);
            col_idx[pos] = src[i];
        }
    }
}

// ---------------------------------------------------------------------------
// GCN gather (bf16 in/out): out[i] = dinv[i]*(hs[i]+sum hs[src]) + b
// 16 lanes/node, uint4 (16 B = 8 bf16)/lane; 4 nodes per wave.
// Edge chunk = 16, idx loaded coalesced by the 16 lanes then shfl-broadcast.
// ---------------------------------------------------------------------------
__global__ void conv_gather_bf16_kernel(const unsigned* __restrict__ hs,
                                        const int* __restrict__ row_ptr,
                                        const int* __restrict__ col_idx,
                                        const float* __restrict__ dinv,
                                        const float* __restrict__ b,
                                        unsigned* __restrict__ outp, int N)
{
    int tid = blockIdx.x * blockDim.x + threadIdx.x;
    int node = tid >> 4;
    int f = tid & 15;           // 16 lanes per node, 16 B each
    if (node >= N) return;
    const uint4* base = reinterpret_cast<const uint4*>(hs);
    float a[8];
    {
        uint4 v = base[(size_t)node * 16 + f];
        a[0] = bf16_lo(v.x); a[1] = bf16_hi(v.x);
        a[2] = bf16_lo(v.y); a[3] = bf16_hi(v.y);
        a[4] = bf16_lo(v.z); a[5] = bf16_hi(v.z);
        a[6] = bf16_lo(v.w); a[7] = bf16_hi(v.w);
    }
    int e = row_ptr[node], end = row_ptr[node + 1];
    while (e < end) {
        int m = end - e;
        if (m >= 16) {
            int idx = col_idx[e + f];
            #pragma unroll 16
            for (int j = 0; j < 16; ++j) {
                int s = __shfl(idx, j, 16);
                uint4 v = base[(size_t)s * 16 + f];
                a[0] += bf16_lo(v.x); a[1] += bf16_hi(v.x);
                a[2] += bf16_lo(v.y); a[3] += bf16_hi(v.y);
                a[4] += bf16_lo(v.z); a[5] += bf16_hi(v.z);
                a[6] += bf16_lo(v.w); a[7] += bf16_hi(v.w);
            }
            e += 16;
        } else {
            int idx = (f < m) ? col_idx[e + f] : 0;
            for (int j = 0; j < m; ++j) {
                int s = __shfl(idx, j, 16);
                uint4 v = base[(size_t)s * 16 + f];
                a[0] += bf16_lo(v.x); a[1] += bf16_hi(v.x);
                a[2] += bf16_lo(v.y); a[3] += bf16_hi(v.y);
                a[4] += bf16_lo(v.z); a[5] += bf16_hi(v.z);
                a[6] += bf16_lo(v.w); a[7] += bf16_hi(v.w);
            }
            e = end;
        }
    }
    float di = dinv[node];
    const float* bb = b + f * 8;
    uint4 o;
    o.x = pack_bf16(fmaf(di, a[0], bb[0]), fmaf(di, a[1], bb[1]));
    o.y = pack_bf16(fmaf(di, a[2], bb[2]), fmaf(di, a[3], bb[3]));
    o.z = pack_bf16(fmaf(di, a[4], bb[4]), fmaf(di, a[5], bb[5]));
    o.w = pack_bf16(fmaf(di, a[6], bb[6]), fmaf(di, a[7], bb[7]));
    reinterpret_cast<uint4*>(outp)[(size_t)node * 16 + f] = o;
}

extern "C" void kernel_launch(void* const* d_in, const int* in_sizes, int n_in,
                              void* d_out, int out_size, void* d_ws, size_t ws_size,
                              hipStream_t stream)
{
    const float* des   = (const float*)d_in[0];
    const float* tweet = (const float*)d_in[1];
    const float* num   = (const float*)d_in[2];
    const float* cat   = (const float*)d_in[3];
    const int*   eidx  = (const int*)d_in[4];
    const float* W_des = (const float*)d_in[5];  const float* b_des = (const float*)d_in[6];
    const float* W_tw  = (const float*)d_in[7];  const float* b_tw  = (const float*)d_in[8];
    const float* W_num = (const float*)d_in[9];  const float* b_num = (const float*)d_in[10];
    const float* W_cat = (const float*)d_in[11]; const float* b_cat = (const float*)d_in[12];
    const float* W_in  = (const float*)d_in[13]; const float* b_in  = (const float*)d_in[14];
    const float* W_g1  = (const float*)d_in[15]; const float* b_g1  = (const float*)d_in[16];
    const float* W_g2  = (const float*)d_in[17]; const float* b_g2  = (const float*)d_in[18];
    const float* W_o1  = (const float*)d_in[19]; const float* b_o1  = (const float*)d_in[20];
    const float* W_o2  = (const float*)d_in[21]; const float* b_o2  = (const float*)d_in[22];
    float* out = (float*)d_out;

    const int N = in_sizes[0] / 768;
    const int E = in_sizes[4] / 2;
    const int* src = eidx;
    const int* dst = eidx + E;

    // workspace layout
    char* ws = (char*)d_ws;
    const size_t szF = (size_t)N * HID * sizeof(float);
    float* F0 = (float*)ws;                    ws += szF;
    float* F1 = (float*)ws;                    ws += szF;
    float* F2 = (float*)ws;                    ws += szF;
    int* cnt      = (int*)ws;                  ws += ((size_t)N * 4 + 255) & ~255ULL;
    int* row_ptr  = (int*)ws;                  ws += (((size_t)N + 1) * 4 + 255) & ~255ULL;
    int* cursor   = (int*)ws;                  ws += ((size_t)N * 4 + 255) & ~255ULL;
    int* part     = (int*)ws;                  ws += 4096;
    float* dinv   = (float*)ws;                ws += ((size_t)N * 4 + 255) & ~255ULL;
    const size_t sz768 = 768 * 32 * sizeof(short);
    const size_t sz128 = 128 * 128 * sizeof(short);
    short* wdes_hi = (short*)ws; ws += sz768;  short* wdes_lo = (short*)ws; ws += sz768;
    short* wtw_hi  = (short*)ws; ws += sz768;  short* wtw_lo  = (short*)ws; ws += sz768;
    short* win_hi  = (short*)ws; ws += sz128;  short* win_lo  = (short*)ws; ws += sz128;
    short* wg1_hi  = (short*)ws; ws += sz128;  short* wg1_lo  = (short*)ws; ws += sz128;
    short* wg2_hi  = (short*)ws; ws += sz128;  short* wg2_lo  = (short*)ws; ws += sz128;
    short* wo1_hi  = (short*)ws; ws += sz128;  short* wo1_lo  = (short*)ws; ws += sz128;
    int* col_idx  = (int*)ws;                  ws += (size_t)E * 4;

    const int B = (N + 255) / 256;

    // ---- weight fragment conversion ----
    {
        dim3 grid(12, 6);
        convert_w_kernel<<<grid, 256, 0, stream>>>(
            W_des, W_tw, W_in, W_g1, W_g2, W_o1,
            wdes_hi, wdes_lo, wtw_hi, wtw_lo, win_hi, win_lo,
            wg1_hi, wg1_lo, wg2_hi, wg2_lo, wo1_hi, wo1_lo);
    }

    // ---- CSR build ----
    hipMemsetAsync(cnt, 0, (size_t)N * sizeof(int), stream);
    hist_kernel<<<1024, 256, 0, stream>>>(dst, cnt, E);
    scan_block_kernel<<<B, 256, 0, stream>>>(cnt, row_ptr, part, N);
    scan_part_kernel<<<1, 512, 0, stream>>>(part, B);
    scan_final_kernel<<<(N + 256) / 256 + 1, 256, 0, stream>>>(row_ptr, part, cursor, cnt, dinv, N, B);
    {
        const int NPART = 4;
        int step = (N + NPART - 1) / NPART;
        for (int p = 0; p < NPART; ++p) {
            int lo = p * step;
            int hi = (lo + step < N) ? lo + step : N;
            scatter_kernel<<<1024, 256, 0, stream>>>(src, dst, cursor, col_idx, E, lo, hi);
        }
    }

    // ---- encoder -> F0 ----
    {
        dim3 grid((N + 63) / 64, 2);
        enc_mfma2_kernel<<<grid, 256, 0, stream>>>(des, tweet, wdes_hi, wdes_lo,
                                                   wtw_hi, wtw_lo, b_des, b_tw, F0, N);
        enc_nc_kernel<<<((size_t)N * 64 + 255) / 256, 256, 0, stream>>>(num, cat, W_num, b_num, W_cat, b_cat, F0, N);
    }

    int ggrid = (N + 127) / 128;
    int cgrid16 = (int)(((size_t)N * 16 + 255) / 256);

    // ---- x1 = lrelu(x0 @ W_in + b_in) -> F1 (f32) ----
    gemm_mfma_kernel<true, true, false, false, false, false><<<ggrid, 512, 0, stream>>>(
        F0, win_hi, win_lo, b_in, nullptr, nullptr, nullptr, F1, N);

    // ---- conv1: hs1 = (x1 @ W_g1)*dinv -> F2 (bf16); c1 = gather -> F0 (bf16) ----
    gemm_mfma_kernel<false, false, true, true, false, false><<<ggrid, 512, 0, stream>>>(
        F1, wg1_hi, wg1_lo, nullptr, dinv, nullptr, nullptr, F2, N);
    conv_gather_bf16_kernel<<<cgrid16, 256, 0, stream>>>((const unsigned*)F2, row_ptr, col_idx, dinv, b_g1, (unsigned*)F0, N);

    // ---- conv2: hs2 = (c1 @ W_g2)*dinv -> F1 (bf16); c2 = gather -> F2 (bf16) ----
    gemm_mfma_kernel<false, false, true, true, false, true><<<ggrid, 512, 0, stream>>>(
        F0, wg2_hi, wg2_lo, nullptr, dinv, nullptr, nullptr, F1, N);
    conv_gather_bf16_kernel<<<cgrid16, 256, 0, stream>>>((const unsigned*)F1, row_ptr, col_idx, dinv, b_g2, (unsigned*)F2, N);

    // ---- out = lrelu(c2 @ W_o1 + b_o1) @ W_o2 + b_o2 (fused, bf16 in) ----
    gemm_mfma_kernel<true, true, false, false, true, true><<<ggrid, 512, 0, stream>>>(
        F2, wo1_hi, wo1_lo, b_o1, nullptr, W_o2, b_o2, out, N);
}

// Round 12
// 877.686 us; speedup vs baseline: 1.2744x; 1.0022x over previous
//
#include <hip/hip_runtime.h>
#include <hip/hip_bf16.h>
#include <cstdint>

#define HID 128

typedef short short8 __attribute__((ext_vector_type(8)));
typedef float f32x4 __attribute__((ext_vector_type(4)));

__device__ __forceinline__ unsigned pack_bf16(float a, float b)
{
    __hip_bfloat16 ha = __float2bfloat16(a);
    __hip_bfloat16 hb = __float2bfloat16(b);
    unsigned short ua = *reinterpret_cast<unsigned short*>(&ha);
    unsigned short ub = *reinterpret_cast<unsigned short*>(&hb);
    return (unsigned)ua | ((unsigned)ub << 16);
}

__device__ __forceinline__ float bf16_lo(unsigned u)
{
    unsigned v = u << 16;
    return *reinterpret_cast<float*>(&v);
}
__device__ __forceinline__ float bf16_hi(unsigned u)
{
    unsigned v = u & 0xffff0000u;
    return *reinterpret_cast<float*>(&v);
}

// truncate-split x = hi + lo (both bf16-representable), for 8 values
__device__ __forceinline__ void split8(const float* v, short8& h, short8& l)
{
    #pragma unroll
    for (int j = 0; j < 8; ++j) {
        unsigned bits = __float_as_uint(v[j]);
        h[j] = (short)(bits >> 16);
        unsigned hb = bits & 0xffff0000u;
        float lof = v[j] - __uint_as_float(hb);
        l[j] = (short)(__float_as_uint(lof) >> 16);
    }
}

// fragment array layout: frag row index = (kc*NT + nt)*64 + lane, 8 bf16 each.
__device__ __forceinline__ short8 frag_ld(const short* __restrict__ base, int tile, int lane)
{
    return *reinterpret_cast<const short8*>(base + (((size_t)tile * 64 + lane) << 3));
}

// ---------------------------------------------------------------------------
// One-shot weight conversion: f32 [K][C] -> fragment-ordered bf16 hi/lo.
// ---------------------------------------------------------------------------
__global__ void convert_w_kernel(
    const float* W0, const float* W1, const float* W2,
    const float* W3, const float* W4, const float* W5,
    short* H0, short* L0, short* H1, short* L1, short* H2, short* L2,
    short* H3, short* L3, short* H4, short* L4, short* H5, short* L5)
{
    int job = blockIdx.y;
    const float* W; short* H; short* L; int K, C;
    switch (job) {
        case 0: W = W0; H = H0; L = L0; K = 768; C = 32;  break;
        case 1: W = W1; H = H1; L = L1; K = 768; C = 32;  break;
        case 2: W = W2; H = H2; L = L2; K = 128; C = 128; break;
        case 3: W = W3; H = H3; L = L3; K = 128; C = 128; break;
        case 4: W = W4; H = H4; L = L4; K = 128; C = 128; break;
        default: W = W5; H = H5; L = L5; K = 128; C = 128; break;
    }
    int NT = C >> 4;
    int rows = (K >> 5) * NT * 64;
    int r = blockIdx.x * blockDim.x + threadIdx.x;
    if (r >= rows) return;
    int lane = r & 63;
    int tile = r >> 6;
    int c = (tile % NT) * 16 + (lane & 15);
    int kbase = (tile / NT) * 32 + ((lane >> 4) & 3) * 8;
    float v[8];
    #pragma unroll
    for (int j = 0; j < 8; ++j) v[j] = W[(size_t)(kbase + j) * C + c];
    short8 h, l;
    split8(v, h, l);
    *reinterpret_cast<short8*>(H + ((size_t)r << 3)) = h;
    *reinterpret_cast<short8*>(L + ((size_t)r << 3)) = l;
}

// ---------------------------------------------------------------------------
// Encoder [N,768]@[768,32], LDS-free split-bf16 MFMA.
// Both A (depth 2) and W (depth 1) software-pipelined; K-loop FULLY unrolled
// so no load is consumed in the iteration it was issued (in-order vmcnt:
// waiting on a just-issued load forces ALL older outstanding loads to
// complete, which was killing R9/R10's prefetch).
// ---------------------------------------------------------------------------
__global__ __launch_bounds__(256, 4) void enc_mfma2_kernel(
    const float* __restrict__ des, const float* __restrict__ tweet,
    const short* __restrict__ wdes_hi, const short* __restrict__ wdes_lo,
    const short* __restrict__ wtw_hi, const short* __restrict__ wtw_lo,
    const float* __restrict__ bd, const float* __restrict__ bt,
    float* __restrict__ x0, int N)
{
    const int mat = blockIdx.y;
    const float* __restrict__ X = mat ? tweet : des;
    const short* __restrict__ WH = mat ? wtw_hi : wdes_hi;
    const short* __restrict__ WL = mat ? wtw_lo : wdes_lo;
    const float* __restrict__ B = mat ? bt : bd;

    const int t = threadIdx.x;
    const int lane = t & 63;
    const int wv = t >> 6;
    const int n0 = blockIdx.x * 64;
    const int arow = n0 + wv * 16 + (lane & 15);
    const bool valid = arow < N;
    const float* __restrict__ ap = X + (size_t)arow * 768 + ((lane >> 4) & 3) * 8;

    f32x4 acc0 = {}, acc1 = {};

    // A ring (depth 2): slot kc&1 holds chunk kc
    float4 a0[2], a1[2];
    #pragma unroll
    for (int d = 0; d < 2; ++d) {
        a0[d] = make_float4(0.f, 0.f, 0.f, 0.f);
        a1[d] = make_float4(0.f, 0.f, 0.f, 0.f);
        if (valid) {
            a0[d] = *reinterpret_cast<const float4*>(ap + d * 32);
            a1[d] = *reinterpret_cast<const float4*>(ap + d * 32 + 4);
        }
    }
    // W current (pipelined by 1)
    short8 whc0 = frag_ld(WH, 0, lane), wlc0 = frag_ld(WL, 0, lane);
    short8 whc1 = frag_ld(WH, 1, lane), wlc1 = frag_ld(WL, 1, lane);

    #pragma unroll
    for (int kc = 0; kc < 24; ++kc) {
        const int slot = kc & 1;
        float4 u0 = a0[slot], u1 = a1[slot];
        // refill A slot with kc+2 (consumed 2 iterations later)
        if (kc < 22 && valid) {
            a0[slot] = *reinterpret_cast<const float4*>(ap + (kc + 2) * 32);
            a1[slot] = *reinterpret_cast<const float4*>(ap + (kc + 2) * 32 + 4);
        }
        // snapshot current W, then issue next-iteration W loads
        short8 wh0 = whc0, wl0 = wlc0, wh1 = whc1, wl1 = wlc1;
        if (kc < 23) {
            whc0 = frag_ld(WH, (kc + 1) * 2 + 0, lane);
            wlc0 = frag_ld(WL, (kc + 1) * 2 + 0, lane);
            whc1 = frag_ld(WH, (kc + 1) * 2 + 1, lane);
            wlc1 = frag_ld(WL, (kc + 1) * 2 + 1, lane);
        }
        float av[8] = {u0.x, u0.y, u0.z, u0.w, u1.x, u1.y, u1.z, u1.w};
        short8 ah, al;
        split8(av, ah, al);
        acc0 = __builtin_amdgcn_mfma_f32_16x16x32_bf16(ah, wh0, acc0, 0, 0, 0);
        acc1 = __builtin_amdgcn_mfma_f32_16x16x32_bf16(ah, wh1, acc1, 0, 0, 0);
        acc0 = __builtin_amdgcn_mfma_f32_16x16x32_bf16(ah, wl0, acc0, 0, 0, 0);
        acc1 = __builtin_amdgcn_mfma_f32_16x16x32_bf16(ah, wl1, acc1, 0, 0, 0);
        acc0 = __builtin_amdgcn_mfma_f32_16x16x32_bf16(al, wh0, acc0, 0, 0, 0);
        acc1 = __builtin_amdgcn_mfma_f32_16x16x32_bf16(al, wh1, acc1, 0, 0, 0);
    }

    const int cl = lane & 15;
    float b0 = B[cl], b1 = B[16 + cl];
    const int nodeb = n0 + wv * 16 + (lane >> 4) * 4;
    #pragma unroll
    for (int r = 0; r < 4; ++r) {
        int node = nodeb + r;
        if (node < N) {
            float v0 = acc0[r] + b0; v0 = v0 > 0.f ? v0 : 0.01f * v0;
            float v1 = acc1[r] + b1; v1 = v1 > 0.f ? v1 : 0.01f * v1;
            x0[(size_t)node * HID + mat * 32 + cl] = v0;
            x0[(size_t)node * HID + mat * 32 + 16 + cl] = v1;
        }
    }
}

// x0[:,64:96] = lrelu(num @ W_num + b), x0[:,96:128] = lrelu(cat @ W_cat + b)
__global__ void enc_nc_kernel(const float* __restrict__ num, const float* __restrict__ cat,
                              const float* __restrict__ Wn, const float* __restrict__ bn,
                              const float* __restrict__ Wc, const float* __restrict__ bc,
                              float* __restrict__ x0, int N)
{
    int tid = blockIdx.x * blockDim.x + threadIdx.x;
    int col = tid & 63;
    int node = tid >> 6;
    if (node >= N) return;
    float a;
    if (col < 32) {
        const float* r = num + (size_t)node * 5;
        float acc = bn[col];
        #pragma unroll
        for (int k = 0; k < 5; ++k) acc = fmaf(r[k], Wn[k * 32 + col], acc);
        a = acc;
    } else {
        int c = col & 31;
        a = fmaf(cat[node], Wc[c], bc[c]);
    }
    a = a > 0.f ? a : 0.01f * a;
    x0[(size_t)node * HID + 64 + col] = a;
}

// ---------------------------------------------------------------------------
// Dense [N,128]@[128,128], LDS-free split-bf16 MFMA. (R10 structure)
// ---------------------------------------------------------------------------
template<bool BIAS, bool LRELU, bool DINV, bool BF16OUT, bool OUT2, bool BF16IN>
__global__ __launch_bounds__(512, 4) void gemm_mfma_kernel(
    const void* __restrict__ inp, const short* __restrict__ WH, const short* __restrict__ WL,
    const float* __restrict__ b, const float* __restrict__ dinv,
    const float* __restrict__ W2, const float* __restrict__ b2,
    void* __restrict__ outp, int N)
{
    const int t = threadIdx.x;
    const int lane = t & 63;
    const int wv = t >> 6;
    const int n0 = blockIdx.x * 128;
    const int arow = n0 + wv * 16 + (lane & 15);
    const bool valid = arow < N;

    f32x4 acc[8] = {};

    #pragma unroll
    for (int kc = 0; kc < 4; ++kc) {
        short8 ah = {}, al = {};
        if (BF16IN) {
            if (valid) {
                const short* apb = reinterpret_cast<const short*>(inp)
                                   + (size_t)arow * HID + ((lane >> 4) & 3) * 8;
                ah = *reinterpret_cast<const short8*>(apb + kc * 32);
            }
        } else {
            float av[8] = {};
            if (valid) {
                const float* ap = reinterpret_cast<const float*>(inp)
                                  + (size_t)arow * HID + ((lane >> 4) & 3) * 8;
                float4 u0 = *reinterpret_cast<const float4*>(ap + kc * 32);
                float4 u1 = *reinterpret_cast<const float4*>(ap + kc * 32 + 4);
                av[0] = u0.x; av[1] = u0.y; av[2] = u0.z; av[3] = u0.w;
                av[4] = u1.x; av[5] = u1.y; av[6] = u1.z; av[7] = u1.w;
            }
            split8(av, ah, al);
        }
        #pragma unroll
        for (int nt = 0; nt < 8; ++nt) {
            short8 wh = frag_ld(WH, kc * 8 + nt, lane);
            short8 wl = frag_ld(WL, kc * 8 + nt, lane);
            acc[nt] = __builtin_amdgcn_mfma_f32_16x16x32_bf16(ah, wh, acc[nt], 0, 0, 0);
            acc[nt] = __builtin_amdgcn_mfma_f32_16x16x32_bf16(ah, wl, acc[nt], 0, 0, 0);
            if (!BF16IN)
                acc[nt] = __builtin_amdgcn_mfma_f32_16x16x32_bf16(al, wh, acc[nt], 0, 0, 0);
        }
    }

    const int cl = lane & 15;
    const int nodeb = n0 + wv * 16 + (lane >> 4) * 4;

    if (OUT2) {
        float p0[4] = {}, p1[4] = {};
        #pragma unroll
        for (int nt = 0; nt < 8; ++nt) {
            int c = nt * 16 + cl;
            float bb = BIAS ? b[c] : 0.f;
            float w20 = W2[c * 2 + 0], w21 = W2[c * 2 + 1];
            #pragma unroll
            for (int r = 0; r < 4; ++r) {
                float v = acc[nt][r] + bb;
                if (LRELU) v = v > 0.f ? v : 0.01f * v;
                p0[r] = fmaf(v, w20, p0[r]);
                p1[r] = fmaf(v, w21, p1[r]);
            }
        }
        #pragma unroll
        for (int r = 0; r < 4; ++r) {
            #pragma unroll
            for (int m = 1; m < 16; m <<= 1) {
                p0[r] += __shfl_xor(p0[r], m);
                p1[r] += __shfl_xor(p1[r], m);
            }
        }
        if (cl == 0) {
            float* out = reinterpret_cast<float*>(outp);
            #pragma unroll
            for (int r = 0; r < 4; ++r) {
                int node = nodeb + r;
                if (node < N) {
                    out[(size_t)node * 2 + 0] = p0[r] + b2[0];
                    out[(size_t)node * 2 + 1] = p1[r] + b2[1];
                }
            }
        }
        return;
    }

    float di[4];
    if (DINV) {
        #pragma unroll
        for (int r = 0; r < 4; ++r)
            di[r] = (nodeb + r < N) ? dinv[nodeb + r] : 0.f;
    }
    #pragma unroll
    for (int nt = 0; nt < 8; ++nt) {
        int c = nt * 16 + cl;
        float bb = BIAS ? b[c] : 0.f;
        #pragma unroll
        for (int r = 0; r < 4; ++r) {
            float v = acc[nt][r] + bb;
            if (LRELU) v = v > 0.f ? v : 0.01f * v;
            if (DINV)  v *= di[r];
            int node = nodeb + r;
            if (BF16OUT) {
                float pv = __shfl_xor(v, 1);
                if ((lane & 1) == 0 && node < N) {
                    unsigned u = pack_bf16(v, pv);
                    reinterpret_cast<unsigned*>(outp)[(size_t)node * (HID / 2) + (c >> 1)] = u;
                }
            } else {
                if (node < N)
                    reinterpret_cast<float*>(outp)[(size_t)node * HID + c] = v;
            }
        }
    }
}

// ---------------------------------------------------------------------------
// CSR build: histogram -> exclusive scan -> range-partitioned scatter
// ---------------------------------------------------------------------------
__global__ void hist_kernel(const int* __restrict__ dst, int* __restrict__ cnt, int E)
{
    int i = blockIdx.x * blockDim.x + threadIdx.x;
    int stride = gridDim.x * blockDim.x;
    for (; i < E; i += stride) atomicAdd(&cnt[dst[i]], 1);
}

__global__ void scan_block_kernel(const int* __restrict__ cnt, int* __restrict__ excl_out,
                                  int* __restrict__ part, int N)
{
    __shared__ int s[256];
    int t = threadIdx.x;
    int i = blockIdx.x * 256 + t;
    int v = (i < N) ? cnt[i] : 0;
    s[t] = v;
    __syncthreads();
    #pragma unroll
    for (int off = 1; off < 256; off <<= 1) {
        int x = (t >= off) ? s[t - off] : 0;
        __syncthreads();
        s[t] += x;
        __syncthreads();
    }
    int incl = s[t];
    if (i < N) excl_out[i] = incl - v;
    if (t == 255) part[blockIdx.x] = incl;
}

__global__ void scan_part_kernel(int* __restrict__ part, int B)
{
    __shared__ int s[512];
    int t = threadIdx.x;
    int v = (t < B) ? part[t] : 0;
    s[t] = v;
    __syncthreads();
    #pragma unroll
    for (int off = 1; off < 512; off <<= 1) {
        int x = (t >= off) ? s[t - off] : 0;
        __syncthreads();
        s[t] += x;
        __syncthreads();
    }
    int incl = s[t];
    if (t < B) part[t] = incl - v;
    if (t == B - 1) part[B] = incl;
}

__global__ void scan_final_kernel(int* __restrict__ row_ptr, const int* __restrict__ part,
                                  int* __restrict__ cursor, const int* __restrict__ cnt,
                                  float* __restrict__ dinv, int N, int B)
{
    int i = blockIdx.x * blockDim.x + threadIdx.x;
    if (i < N) {
        int rp = row_ptr[i] + part[i >> 8];
        row_ptr[i] = rp;
        cursor[i] = rp;
        dinv[i] = rsqrtf((float)(cnt[i] + 1));
    } else if (i == N) {
        row_ptr[N] = part[B];
    }
}

__global__ void scatter_kernel(const int* __restrict__ src, const int* __restrict__ dst,
                               int* __restrict__ cursor, int* __restrict__ col_idx,
                               int E, int lo, int hi)
{
    int i = blockIdx.x * blockDim.x + threadIdx.x;
    int stride = gridDim.x * blockDim.x;
    for (; i < E; i += stride) {
        int d = dst[i];
        if (d >= lo && d < hi) {
            int pos = atomicAdd(&cursor[d], 1);
            col_idx[pos] = src[i];
        }
    }
}

// ---------------------------------------------------------------------------
// GCN gather (bf16 in/out): out[i] = dinv[i]*(hs[i]+sum hs[src]) + b
// 16 lanes/node, uint4/lane; edge-chunk idx prefetched one chunk ahead.
// ---------------------------------------------------------------------------
__global__ void conv_gather_bf16_kernel(const unsigned* __restrict__ hs,
                                        const int* __restrict__ row_ptr,
                                        const int* __restrict__ col_idx,
                                        const float* __restrict__ dinv,
                                        const float* __restrict__ b,
                                        unsigned* __restrict__ outp, int N)
{
    int tid = blockIdx.x * blockDim.x + threadIdx.x;
    int node = tid >> 4;
    int f = tid & 15;           // 16 lanes per node, 16 B each
    if (node >= N) return;
    const uint4* base = reinterpret_cast<const uint4*>(hs);
    float a[8];
    {
        uint4 v = base[(size_t)node * 16 + f];
        a[0] = bf16_lo(v.x); a[1] = bf16_hi(v.x);
        a[2] = bf16_lo(v.y); a[3] = bf16_hi(v.y);
        a[4] = bf16_lo(v.z); a[5] = bf16_hi(v.z);
        a[6] = bf16_lo(v.w); a[7] = bf16_hi(v.w);
    }
    int e = row_ptr[node], end = row_ptr[node + 1];
    int idx = (e + f < end) ? col_idx[e + f] : 0;    // first chunk prefetched
    while (e < end) {
        int m = end - e;
        int curidx = idx;
        if (e + 16 + f < end) idx = col_idx[e + 16 + f];   // prefetch next chunk
        if (m >= 16) {
            #pragma unroll 16
            for (int j = 0; j < 16; ++j) {
                int s = __shfl(curidx, j, 16);
                uint4 v = base[(size_t)s * 16 + f];
                a[0] += bf16_lo(v.x); a[1] += bf16_hi(v.x);
                a[2] += bf16_lo(v.y); a[3] += bf16_hi(v.y);
                a[4] += bf16_lo(v.z); a[5] += bf16_hi(v.z);
                a[6] += bf16_lo(v.w); a[7] += bf16_hi(v.w);
            }
            e += 16;
        } else {
            for (int j = 0; j < m; ++j) {
                int s = __shfl(curidx, j, 16);
                uint4 v = base[(size_t)s * 16 + f];
                a[0] += bf16_lo(v.x); a[1] += bf16_hi(v.x);
                a[2] += bf16_lo(v.y); a[3] += bf16_hi(v.y);
                a[4] += bf16_lo(v.z); a[5] += bf16_hi(v.z);
                a[6] += bf16_lo(v.w); a[7] += bf16_hi(v.w);
            }
            e = end;
        }
    }
    float di = dinv[node];
    const float* bb = b + f * 8;
    uint4 o;
    o.x = pack_bf16(fmaf(di, a[0], bb[0]), fmaf(di, a[1], bb[1]));
    o.y = pack_bf16(fmaf(di, a[2], bb[2]), fmaf(di, a[3], bb[3]));
    o.z = pack_bf16(fmaf(di, a[4], bb[4]), fmaf(di, a[5], bb[5]));
    o.w = pack_bf16(fmaf(di, a[6], bb[6]), fmaf(di, a[7], bb[7]));
    reinterpret_cast<uint4*>(outp)[(size_t)node * 16 + f] = o;
}

extern "C" void kernel_launch(void* const* d_in, const int* in_sizes, int n_in,
                              void* d_out, int out_size, void* d_ws, size_t ws_size,
                              hipStream_t stream)
{
    const float* des   = (const float*)d_in[0];
    const float* tweet = (const float*)d_in[1];
    const float* num   = (const float*)d_in[2];
    const float* cat   = (const float*)d_in[3];
    const int*   eidx  = (const int*)d_in[4];
    const float* W_des = (const float*)d_in[5];  const float* b_des = (const float*)d_in[6];
    const float* W_tw  = (const float*)d_in[7];  const float* b_tw  = (const float*)d_in[8];
    const float* W_num = (const float*)d_in[9];  const float* b_num = (const float*)d_in[10];
    const float* W_cat = (const float*)d_in[11]; const float* b_cat = (const float*)d_in[12];
    const float* W_in  = (const float*)d_in[13]; const float* b_in  = (const float*)d_in[14];
    const float* W_g1  = (const float*)d_in[15]; const float* b_g1  = (const float*)d_in[16];
    const float* W_g2  = (const float*)d_in[17]; const float* b_g2  = (const float*)d_in[18];
    const float* W_o1  = (const float*)d_in[19]; const float* b_o1  = (const float*)d_in[20];
    const float* W_o2  = (const float*)d_in[21]; const float* b_o2  = (const float*)d_in[22];
    float* out = (float*)d_out;

    const int N = in_sizes[0] / 768;
    const int E = in_sizes[4] / 2;
    const int* src = eidx;
    const int* dst = eidx + E;

    // workspace layout
    char* ws = (char*)d_ws;
    const size_t szF = (size_t)N * HID * sizeof(float);
    float* F0 = (float*)ws;                    ws += szF;
    float* F1 = (float*)ws;                    ws += szF;
    float* F2 = (float*)ws;                    ws += szF;
    int* cnt      = (int*)ws;                  ws += ((size_t)N * 4 + 255) & ~255ULL;
    int* row_ptr  = (int*)ws;                  ws += (((size_t)N + 1) * 4 + 255) & ~255ULL;
    int* cursor   = (int*)ws;                  ws += ((size_t)N * 4 + 255) & ~255ULL;
    int* part     = (int*)ws;                  ws += 4096;
    float* dinv   = (float*)ws;                ws += ((size_t)N * 4 + 255) & ~255ULL;
    const size_t sz768 = 768 * 32 * sizeof(short);
    const size_t sz128 = 128 * 128 * sizeof(short);
    short* wdes_hi = (short*)ws; ws += sz768;  short* wdes_lo = (short*)ws; ws += sz768;
    short* wtw_hi  = (short*)ws; ws += sz768;  short* wtw_lo  = (short*)ws; ws += sz768;
    short* win_hi  = (short*)ws; ws += sz128;  short* win_lo  = (short*)ws; ws += sz128;
    short* wg1_hi  = (short*)ws; ws += sz128;  short* wg1_lo  = (short*)ws; ws += sz128;
    short* wg2_hi  = (short*)ws; ws += sz128;  short* wg2_lo  = (short*)ws; ws += sz128;
    short* wo1_hi  = (short*)ws; ws += sz128;  short* wo1_lo  = (short*)ws; ws += sz128;
    int* col_idx  = (int*)ws;                  ws += (size_t)E * 4;

    const int B = (N + 255) / 256;

    // ---- weight fragment conversion ----
    {
        dim3 grid(12, 6);
        convert_w_kernel<<<grid, 256, 0, stream>>>(
            W_des, W_tw, W_in, W_g1, W_g2, W_o1,
            wdes_hi, wdes_lo, wtw_hi, wtw_lo, win_hi, win_lo,
            wg1_hi, wg1_lo, wg2_hi, wg2_lo, wo1_hi, wo1_lo);
    }

    // ---- CSR build ----
    hipMemsetAsync(cnt, 0, (size_t)N * sizeof(int), stream);
    hist_kernel<<<1024, 256, 0, stream>>>(dst, cnt, E);
    scan_block_kernel<<<B, 256, 0, stream>>>(cnt, row_ptr, part, N);
    scan_part_kernel<<<1, 512, 0, stream>>>(part, B);
    scan_final_kernel<<<(N + 256) / 256 + 1, 256, 0, stream>>>(row_ptr, part, cursor, cnt, dinv, N, B);
    {
        const int NPART = 4;
        int step = (N + NPART - 1) / NPART;
        for (int p = 0; p < NPART; ++p) {
            int lo = p * step;
            int hi = (lo + step < N) ? lo + step : N;
            scatter_kernel<<<1024, 256, 0, stream>>>(src, dst, cursor, col_idx, E, lo, hi);
        }
    }

    // ---- encoder -> F0 ----
    {
        dim3 grid((N + 63) / 64, 2);
        enc_mfma2_kernel<<<grid, 256, 0, stream>>>(des, tweet, wdes_hi, wdes_lo,
                                                   wtw_hi, wtw_lo, b_des, b_tw, F0, N);
        enc_nc_kernel<<<((size_t)N * 64 + 255) / 256, 256, 0, stream>>>(num, cat, W_num, b_num, W_cat, b_cat, F0, N);
    }

    int ggrid = (N + 127) / 128;
    int cgrid16 = (int)(((size_t)N * 16 + 255) / 256);

    // ---- x1 = lrelu(x0 @ W_in + b_in) -> F1 (f32) ----
    gemm_mfma_kernel<true, true, false, false, false, false><<<ggrid, 512, 0, stream>>>(
        F0, win_hi, win_lo, b_in, nullptr, nullptr, nullptr, F1, N);

    // ---- conv1: hs1 = (x1 @ W_g1)*dinv -> F2 (bf16); c1 = gather -> F0 (bf16) ----
    gemm_mfma_kernel<false, false, true, true, false, false><<<ggrid, 512, 0, stream>>>(
        F1, wg1_hi, wg1_lo, nullptr, dinv, nullptr, nullptr, F2, N);
    conv_gather_bf16_kernel<<<cgrid16, 256, 0, stream>>>((const unsigned*)F2, row_ptr, col_idx, dinv, b_g1, (unsigned*)F0, N);

    // ---- conv2: hs2 = (c1 @ W_g2)*dinv -> F1 (bf16); c2 = gather -> F2 (bf16) ----
    gemm_mfma_kernel<false, false, true, true, false, true><<<ggrid, 512, 0, stream>>>(
        F0, wg2_hi, wg2_lo, nullptr, dinv, nullptr, nullptr, F1, N);
    conv_gather_bf16_kernel<<<cgrid16, 256, 0, stream>>>((const unsigned*)F1, row_ptr, col_idx, dinv, b_g2, (unsigned*)F2, N);

    // ---- out = lrelu(c2 @ W_o1 + b_o1) @ W_o2 + b_o2 (fused, bf16 in) ----
    gemm_mfma_kernel<true, true, false, false, true, true><<<ggrid, 512, 0, stream>>>(
        F2, wo1_hi, wo1_lo, b_o1, nullptr, W_o2, b_o2, out, N);
}